// Round 12
// baseline (853.047 us; speedup 1.0000x reference)
//
#include <hip/hip_runtime.h>

#define NPTS 8192
#define HDIM 64
#define KNN 16
#define LOG2E 1.4426950408889634f

// ---- spatial grid ----
#define G1D 40
#define G3 (G1D * G1D * G1D)        // 64000 cells
#define CPT (G3 / 256)              // 250 cells per scan thread
#define GH (9.0f / G1D)             // 0.225 cell size
#define GSCALE (G1D / 9.0f)
#define SHELL_MAXR 6
#define SHELL_TOT 2197              // 13^3 packed cell offsets

typedef __attribute__((ext_vector_type(8))) short bf8_t;   // 8 bf16
typedef __attribute__((ext_vector_type(4))) float f4_t;    // MFMA C/D
#define MFMA16(a, b, c) __builtin_amdgcn_mfma_f32_16x16x32_bf16(a, b, c, 0, 0, 0)

__device__ __forceinline__ float fast_exp(float x) {
    float y = x * LOG2E;
    float r;
    asm volatile("v_exp_f32 %0, %1\n\ts_nop 1" : "=v"(r) : "v"(y));
    return r;
}
__device__ __forceinline__ unsigned short f2b(float x) {   // f32 -> bf16 RNE
    unsigned v = __float_as_uint(x);
    return (unsigned short)((v + 0x7FFFu + ((v >> 16) & 1u)) >> 16);
}

// ---- ws layout (bytes) ----
#define OFF_QW     0u
#define OFF_KW     (4u << 20)
#define OFF_VW     (8u << 20)
#define OFF_FRAG   (12u << 20)                     // 24 KB
#define OFF_KNN    ((12u << 20) + 32768u)          // 1 MB
#define OFF_CCNT   (OFF_KNN + (1u << 20))          // 512000
#define OFF_CSTART (OFF_CCNT + 512000u)
#define OFF_CURSOR (OFF_CSTART + 512000u)
#define OFF_PTIDX  (OFF_CURSOR + 512000u)          // 64 KB
#define OFF_PTPACK (OFF_PTIDX + 65536u)            // 256 KB
#define OFF_SHELL  (OFF_PTPACK + 262144u)          // ~8.8 KB
#define NEED_GRID  (size_t)(OFF_SHELL + 8832u)
#define NEED_R11   (size_t)((12u << 20) + 24576u)

// ---------------------------------------------------------------------------
// prefrag: pack Wp2/Wt1/Wt2 into MFMA B-frag order (proven R11).
// ---------------------------------------------------------------------------
__global__ void prefrag_kernel(const float* __restrict__ Wp2,
                               const float* __restrict__ Wt1,
                               const float* __restrict__ Wt2,
                               unsigned short* __restrict__ dst)
{
    int i = blockIdx.x * 256 + threadIdx.x;
    if (i >= 3 * 4096) return;
    int st = i >> 12, e = i & 4095;
    const float* W = (st == 0) ? Wp2 : (st == 1) ? Wt1 : Wt2;
    int k = e >> 6, n = e & 63;
    int s = k >> 5, quad = (k >> 3) & 3, j = k & 7;
    int t = n >> 4, l = quad * 16 + (n & 15);
    dst[st * 4096 + (s * 4 + t) * 512 + l * 8 + j] = f2b(W[e]);
}

// ---------------------------------------------------------------------------
// shell table: cell offsets sorted by Chebyshev ring, packed 4b/axis (+6).
// ---------------------------------------------------------------------------
__global__ void build_shell_kernel(int* __restrict__ shellOff,
                                   int* __restrict__ shellStart)
{
    if (threadIdx.x != 0 || blockIdx.x != 0) return;
    int cnt = 0;
    shellStart[0] = 0;
    for (int r = 0; r <= SHELL_MAXR; ++r) {
        for (int dz = -r; dz <= r; ++dz)
            for (int dy = -r; dy <= r; ++dy)
                for (int dx = -r; dx <= r; ++dx) {
                    int m = max(abs(dx), max(abs(dy), abs(dz)));
                    if (m == r)
                        shellOff[cnt++] = ((dz + 6) << 8) | ((dy + 6) << 4) | (dx + 6);
                }
        shellStart[r + 1] = cnt;
    }
}

__global__ void grid_zero_kernel(int* __restrict__ cnt) {
    int i = blockIdx.x * 256 + threadIdx.x;
    if (i < 2 * G3) cnt[i] = 0;
}

__device__ __forceinline__ int cell_of(float4 c4) {
    int cx = min(max((int)floorf((c4.x + 4.5f) * GSCALE), 0), G1D - 1);
    int cy = min(max((int)floorf((c4.y + 4.5f) * GSCALE), 0), G1D - 1);
    int cz = min(max((int)floorf((c4.z + 4.5f) * GSCALE), 0), G1D - 1);
    return (cz * G1D + cy) * G1D + cx;
}

__global__ void grid_count_kernel(const float* __restrict__ xyzp,
                                  int* __restrict__ cnt) {
    int p = blockIdx.x * 256 + threadIdx.x;
    if (p >= 2 * NPTS) return;
    int b = p >> 13;
    float4 c4 = ((const float4*)xyzp)[p];
    atomicAdd(&cnt[b * G3 + cell_of(c4)], 1);
}

__global__ __launch_bounds__(256) void grid_scan_kernel(
    const int* __restrict__ cnt, int* __restrict__ start, int* __restrict__ cursor)
{
    __shared__ int part[256];
    int b = blockIdx.x, t = threadIdx.x;
    const int* c = cnt + b * G3;
    int s = 0;
    for (int j = 0; j < CPT; ++j) s += c[t * CPT + j];
    part[t] = s;
    __syncthreads();
    for (int off = 1; off < 256; off <<= 1) {
        int v = (t >= off) ? part[t - off] : 0;
        __syncthreads();
        part[t] += v;
        __syncthreads();
    }
    int run = part[t] - s;                        // exclusive prefix
    int* st = start + b * G3;
    int* cu = cursor + b * G3;
    for (int j = 0; j < CPT; ++j) {
        int cc = c[t * CPT + j];
        st[t * CPT + j] = run;
        cu[t * CPT + j] = run;
        run += cc;
    }
}

__global__ void grid_scatter_kernel(const float* __restrict__ xyzp,
                                    int* __restrict__ cursor,
                                    int* __restrict__ ptIdx,
                                    float4* __restrict__ ptPacked) {
    int p = blockIdx.x * 256 + threadIdx.x;
    if (p >= 2 * NPTS) return;
    int b = p >> 13, n = p & (NPTS - 1);
    float4 c4 = ((const float4*)xyzp)[p];
    int dst = atomicAdd(&cursor[b * G3 + cell_of(c4)], 1);
    ptIdx[b * NPTS + dst] = n;
    ptPacked[b * NPTS + dst] =
        make_float4(c4.x, c4.y, c4.z, 0.5f * (c4.x * c4.x + c4.y * c4.y + c4.z * c4.z));
}

// ---------------------------------------------------------------------------
// grid KNN: wave per query; exact via ring bound; brute-force fallback inline.
// ---------------------------------------------------------------------------
__global__ __launch_bounds__(256) void knn_grid_kernel(
    const float* __restrict__ xyzp,
    const int* __restrict__ cellStart, const int* __restrict__ cellCount,
    const int* __restrict__ ptIdx, const float4* __restrict__ ptPacked,
    const int* __restrict__ shellOff, const int* __restrict__ shellStart,
    int* __restrict__ knnIdx)
{
    int w = threadIdx.x >> 6, lane = threadIdx.x & 63;
    int p = blockIdx.x * 4 + w;
    int b = p >> 13;

    float4 q4 = ((const float4*)xyzp)[p];
    float qx = q4.x, qy = q4.y, qz = q4.z;
    float qs = qx * qx + qy * qy + qz * qz;

    float fx = (qx + 4.5f) * GSCALE;
    float fy = (qy + 4.5f) * GSCALE;
    float fz = (qz + 4.5f) * GSCALE;
    int hx = min(max((int)floorf(fx), 0), G1D - 1);
    int hy = min(max((int)floorf(fy), 0), G1D - 1);
    int hz = min(max((int)floorf(fz), 0), G1D - 1);
    float ox = fmaxf(fmaxf(fx - (float)(hx + 1), (float)hx - fx), 0.f);
    float oy = fmaxf(fmaxf(fy - (float)(hy + 1), (float)hy - fy), 0.f);
    float oz = fmaxf(fmaxf(fz - (float)(hz + 1), (float)hz - fz), 0.f);
    float over = fmaxf(ox, fmaxf(oy, oz)) * GH;   // 0 for in-grid queries

    float dh[16]; int ih[16];
    #pragma unroll
    for (int j = 0; j < 16; ++j) { dh[j] = 3.4e38f; ih[j] = 0x7fffffff; }

    bool done = false;
    #pragma unroll 1
    for (int r = 1; r <= SHELL_MAXR && !done; ++r) {
        int s0 = shellStart[(r == 1) ? 0 : r];    // first pass covers rings 0+1
        int s1 = shellStart[r + 1];
        #pragma unroll 1
        for (int base = s0; base < s1; base += 64) {
            int t = base + lane;
            int cstart = 0, ccnt = 0;
            if (t < s1) {
                int pk = shellOff[t];
                int cx = hx + (pk & 15) - 6;
                int cy = hy + ((pk >> 4) & 15) - 6;
                int cz = hz + ((pk >> 8) & 15) - 6;
                if ((unsigned)cx < G1D && (unsigned)cy < G1D && (unsigned)cz < G1D) {
                    int cell = b * G3 + (cz * G1D + cy) * G1D + cx;
                    cstart = cellStart[cell];
                    ccnt = cellCount[cell];
                }
            }
            #pragma unroll 1
            for (int j = 0;; ++j) {
                bool act = j < ccnt;
                if (!__any(act)) break;
                if (act) {
                    float4 c4 = ptPacked[b * NPTS + cstart + j];
                    int idx = ptIdx[b * NPTS + cstart + j];
                    float d2 = fmaf(2.f, c4.w - (qx * c4.x + qy * c4.y + qz * c4.z), qs);
                    if (d2 < dh[15] || (d2 == dh[15] && idx < ih[15])) {
                        dh[15] = d2; ih[15] = idx;
                        #pragma unroll
                        for (int jj = 15; jj >= 1; --jj) {
                            bool sw = (dh[jj] < dh[jj - 1]) ||
                                      (dh[jj] == dh[jj - 1] && ih[jj] < ih[jj - 1]);
                            if (sw) {
                                float td = dh[jj]; dh[jj] = dh[jj - 1]; dh[jj - 1] = td;
                                int ti = ih[jj]; ih[jj] = ih[jj - 1]; ih[jj - 1] = ti;
                            }
                        }
                    }
                }
            }
        }
        // exact termination: unvisited points are >= r*GH - over away
        float B = (float)r * GH - over - 1e-4f;
        if (B > 0.f) {
            float B2 = B * B;
            int cnt = 0;
            #pragma unroll
            for (int jj = 0; jj < 16; ++jj) cnt += (dh[jj] <= B2) ? 1 : 0;
            #pragma unroll
            for (int s = 1; s < 64; s <<= 1) cnt += __shfl_xor(cnt, s);
            if (cnt >= 16) done = true;
        }
    }

    if (!done) {        // rare tail: proven brute-force scan (reset to avoid dups)
        #pragma unroll
        for (int j = 0; j < 16; ++j) { dh[j] = 3.4e38f; ih[j] = 0x7fffffff; }
        const float4* xb4 = (const float4*)xyzp + (size_t)b * NPTS;
        for (int t = 0; t < NPTS / 64; ++t) {
            int m = t * 64 + lane;
            float4 c4 = xb4[m];
            float cs = c4.x * c4.x + c4.y * c4.y + c4.z * c4.z;
            float d2 = qs + cs - 2.0f * (qx * c4.x + qy * c4.y + qz * c4.z);
            if (d2 < dh[15] || (d2 == dh[15] && m < ih[15])) {
                dh[15] = d2; ih[15] = m;
                #pragma unroll
                for (int jj = 15; jj >= 1; --jj) {
                    bool sw = (dh[jj] < dh[jj - 1]) ||
                              (dh[jj] == dh[jj - 1] && ih[jj] < ih[jj - 1]);
                    if (sw) {
                        float td = dh[jj]; dh[jj] = dh[jj - 1]; dh[jj - 1] = td;
                        int ti = ih[jj]; ih[jj] = ih[jj - 1]; ih[jj - 1] = ti;
                    }
                }
            }
        }
    }

    // merge: 16 rounds wave argmin + winner-shift (proven R10)
    int mynb = 0;
    #pragma unroll 1
    for (int r2 = 0; r2 < KNN; ++r2) {
        float d = dh[0]; int i = ih[0];
        #pragma unroll
        for (int s = 1; s < 64; s <<= 1) {
            float dv = __shfl_xor(d, s); int iv = __shfl_xor(i, s);
            if (dv < d || (dv == d && iv < i)) { d = dv; i = iv; }
        }
        if (lane == r2) mynb = i;
        if (ih[0] == i) {
            #pragma unroll
            for (int j = 0; j < 15; ++j) { dh[j] = dh[j + 1]; ih[j] = ih[j + 1]; }
            dh[15] = 3.4e38f; ih[15] = 0x7fffffff;
        }
    }
    if (lane < KNN) knnIdx[(size_t)p * KNN + lane] = mynb;
}

// ---------------------------------------------------------------------------
// proj: q/k/v per point (proven R11).
// ---------------------------------------------------------------------------
__global__ __launch_bounds__(256) void proj_kernel(
    const float* __restrict__ feat,
    const float* __restrict__ Wk, const float* __restrict__ bk,
    const float* __restrict__ Wq, const float* __restrict__ Wks,
    const float* __restrict__ Wv,
    float* __restrict__ qw, float* __restrict__ kw, float* __restrict__ vw)
{
    int w = threadIdx.x >> 6, lane = threadIdx.x & 63;
    int p = blockIdx.x * 4 + w;
    float f = feat[(size_t)p * HDIM + lane];
    float x = bk[lane];
    #pragma unroll 8
    for (int c = 0; c < 64; ++c) x += __shfl(f, c) * Wk[c * 64 + lane];
    float q = 0.f, k = 0.f, v = 0.f;
    #pragma unroll 8
    for (int c = 0; c < 64; ++c) {
        float xc = __shfl(x, c);
        q += xc * Wq[c * 64 + lane];
        k += xc * Wks[c * 64 + lane];
        v += xc * Wv[c * 64 + lane];
    }
    qw[(size_t)p * HDIM + lane] = q;
    kw[(size_t)p * HDIM + lane] = k;
    vw[(size_t)p * HDIM + lane] = v;
}

// ---------------------------------------------------------------------------
// main: MFMA per-neighbor MLPs (proven R11), KNN replaced by idx load.
// ---------------------------------------------------------------------------
__global__ __launch_bounds__(256) void LocalTransformer_80513456931527_kernel(
    const float* __restrict__ xyzp, const float* __restrict__ features,
    const float* __restrict__ Wp1,  const float* __restrict__ bp1,
    const float* __restrict__ bp2,  const float* __restrict__ bt1,
    const float* __restrict__ bt2,
    const float* __restrict__ Wa,   const float* __restrict__ ba,
    const float* __restrict__ qw, const float* __restrict__ kw,
    const float* __restrict__ vw,
    const unsigned short* __restrict__ fragw,
    const int* __restrict__ knnIdx,
    float* __restrict__ out)
{
    __shared__ __align__(16) float sBounce[4][16 * 68 + 4];

    int tid = threadIdx.x, w = tid >> 6, lane = tid & 63;
    int p = blockIdx.x * 4 + w;
    int b = p >> 13;
    float* bb = sBounce[w];

    int quad = lane >> 4, l15 = lane & 15;
    int mynb = knnIdx[(size_t)p * KNN + l15];     // lane holds neighbor (lane&15)
    mynb = min(max(mynb, 0), NPTS - 1);
    int nb_a = mynb;
    int nbm[4];
    #pragma unroll
    for (int r = 0; r < 4; ++r) nbm[r] = __shfl(mynb, quad * 4 + r);

    // pe1 directly in A-frag layout
    const float4 xq4 = *(const float4*)(xyzp + (size_t)p * 4);
    const float4 xn4 = *(const float4*)(xyzp + ((size_t)b * NPTS + nb_a) * 4);
    float rel0 = xq4.x - xn4.x, rel1 = xq4.y - xn4.y;
    float rel2 = xq4.z - xn4.z, rel3 = xq4.w - xn4.w;

    bf8_t pe1f[2];
    #pragma unroll
    for (int s = 0; s < 2; ++s) {
        int hb = s * 32 + quad * 8;
        float W0[8], W1[8], W2[8], W3[8], Bb[8];
        *(float4*)&W0[0] = *(const float4*)(Wp1 +       hb);
        *(float4*)&W0[4] = *(const float4*)(Wp1 +       hb + 4);
        *(float4*)&W1[0] = *(const float4*)(Wp1 +  64 + hb);
        *(float4*)&W1[4] = *(const float4*)(Wp1 +  64 + hb + 4);
        *(float4*)&W2[0] = *(const float4*)(Wp1 + 128 + hb);
        *(float4*)&W2[4] = *(const float4*)(Wp1 + 128 + hb + 4);
        *(float4*)&W3[0] = *(const float4*)(Wp1 + 192 + hb);
        *(float4*)&W3[4] = *(const float4*)(Wp1 + 192 + hb + 4);
        *(float4*)&Bb[0] = *(const float4*)(bp1 + hb);
        *(float4*)&Bb[4] = *(const float4*)(bp1 + hb + 4);
        #pragma unroll
        for (int j = 0; j < 8; ++j) {
            float a = Bb[j] + rel0 * W0[j] + rel1 * W1[j]
                            + rel2 * W2[j] + rel3 * W3[j];
            pe1f[s][j] = (short)f2b(fmaxf(a, 0.f));
        }
    }

    const bf8_t* BW = (const bf8_t*)fragw;
    f4_t pe2c[4];
    #pragma unroll
    for (int t = 0; t < 4; ++t) {
        f4_t acc = {0.f, 0.f, 0.f, 0.f};
        acc = MFMA16(pe1f[0], BW[0 * 512 + (0 * 4 + t) * 64 + lane], acc);
        acc = MFMA16(pe1f[1], BW[0 * 512 + (1 * 4 + t) * 64 + lane], acc);
        float bias = bp2[t * 16 + l15];
        #pragma unroll
        for (int r = 0; r < 4; ++r) acc[r] += bias;
        pe2c[t] = acc;
    }

    f4_t ainc[4], vpec[4];
    #pragma unroll
    for (int t = 0; t < 4; ++t) {
        float qv = qw[(size_t)p * HDIM + t * 16 + l15];
        #pragma unroll
        for (int r = 0; r < 4; ++r) {
            size_t nbo = ((size_t)b * NPTS + nbm[r]) * HDIM + t * 16 + l15;
            ainc[t][r] = qv - kw[nbo] + pe2c[t][r];
            vpec[t][r] = vw[nbo] + pe2c[t][r];
        }
    }

    #pragma unroll
    for (int t = 0; t < 4; ++t)
        #pragma unroll
        for (int r = 0; r < 4; ++r)
            bb[(quad * 4 + r) * 68 + t * 16 + l15] = ainc[t][r];
    asm volatile("s_waitcnt lgkmcnt(0)" ::: "memory");
    bf8_t af[2];
    #pragma unroll
    for (int s = 0; s < 2; ++s) {
        float tmp[8];
        *(float4*)&tmp[0] = *(const float4*)&bb[l15 * 68 + s * 32 + quad * 8];
        *(float4*)&tmp[4] = *(const float4*)&bb[l15 * 68 + s * 32 + quad * 8 + 4];
        #pragma unroll
        for (int j = 0; j < 8; ++j) af[s][j] = (short)f2b(tmp[j]);
    }

    f4_t t1c[4];
    #pragma unroll
    for (int t = 0; t < 4; ++t) {
        f4_t acc = {0.f, 0.f, 0.f, 0.f};
        acc = MFMA16(af[0], BW[1 * 512 + (0 * 4 + t) * 64 + lane], acc);
        acc = MFMA16(af[1], BW[1 * 512 + (1 * 4 + t) * 64 + lane], acc);
        float bias = bt1[t * 16 + l15];
        #pragma unroll
        for (int r = 0; r < 4; ++r) t1c[t][r] = fmaxf(acc[r] + bias, 0.f);
    }

    asm volatile("s_waitcnt lgkmcnt(0)" ::: "memory");
    #pragma unroll
    for (int t = 0; t < 4; ++t)
        #pragma unroll
        for (int r = 0; r < 4; ++r)
            bb[(quad * 4 + r) * 68 + t * 16 + l15] = t1c[t][r];
    asm volatile("s_waitcnt lgkmcnt(0)" ::: "memory");
    bf8_t tf[2];
    #pragma unroll
    for (int s = 0; s < 2; ++s) {
        float tmp[8];
        *(float4*)&tmp[0] = *(const float4*)&bb[l15 * 68 + s * 32 + quad * 8];
        *(float4*)&tmp[4] = *(const float4*)&bb[l15 * 68 + s * 32 + quad * 8 + 4];
        #pragma unroll
        for (int j = 0; j < 8; ++j) tf[s][j] = (short)f2b(tmp[j]);
    }

    f4_t lgc[4];
    #pragma unroll
    for (int t = 0; t < 4; ++t) {
        f4_t acc = {0.f, 0.f, 0.f, 0.f};
        acc = MFMA16(tf[0], BW[2 * 512 + (0 * 4 + t) * 64 + lane], acc);
        acc = MFMA16(tf[1], BW[2 * 512 + (1 * 4 + t) * 64 + lane], acc);
        float bias = bt2[t * 16 + l15];
        #pragma unroll
        for (int r = 0; r < 4; ++r) lgc[t][r] = (acc[r] + bias) * 0.125f;
    }

    float res[4];
    #pragma unroll
    for (int t = 0; t < 4; ++t) {
        float m0 = fmaxf(fmaxf(lgc[t][0], lgc[t][1]), fmaxf(lgc[t][2], lgc[t][3]));
        m0 = fmaxf(m0, __shfl_xor(m0, 16));
        m0 = fmaxf(m0, __shfl_xor(m0, 32));
        float e0 = fast_exp(lgc[t][0] - m0), e1 = fast_exp(lgc[t][1] - m0);
        float e2 = fast_exp(lgc[t][2] - m0), e3 = fast_exp(lgc[t][3] - m0);
        float sl = e0 + e1 + e2 + e3;
        float rl = e0 * vpec[t][0] + e1 * vpec[t][1]
                 + e2 * vpec[t][2] + e3 * vpec[t][3];
        sl += __shfl_xor(sl, 16); sl += __shfl_xor(sl, 32);
        rl += __shfl_xor(rl, 16); rl += __shfl_xor(rl, 32);
        res[t] = rl / sl;
    }

    float rh = (quad == 0) ? res[0] : (quad == 1) ? res[1]
             : (quad == 2) ? res[2] : res[3];
    float f = features[(size_t)p * HDIM + lane];
    float o = ba[lane];
    #pragma unroll 8
    for (int c = 0; c < 64; ++c) o += __shfl(rh, c) * Wa[c * 64 + lane];
    out[(size_t)p * HDIM + lane] = o + f;
}

// ---------------------------------------------------------------------------
// R11 main with inline KNN (fallback when ws in [12, 14.8) MB — proven).
// ---------------------------------------------------------------------------
__global__ __launch_bounds__(256) void attn_knn_main_kernel(
    const float* __restrict__ xyzp, const float* __restrict__ features,
    const float* __restrict__ Wp1,  const float* __restrict__ bp1,
    const float* __restrict__ bp2,  const float* __restrict__ bt1,
    const float* __restrict__ bt2,
    const float* __restrict__ Wa,   const float* __restrict__ ba,
    const float* __restrict__ qw, const float* __restrict__ kw,
    const float* __restrict__ vw,
    const unsigned short* __restrict__ fragw,
    float* __restrict__ out)
{
    __shared__ __align__(16) float sBounce[4][16 * 68 + 4];
    int tid = threadIdx.x, w = tid >> 6, lane = tid & 63;
    int p = blockIdx.x * 4 + w;
    int b = p >> 13, n = p & (NPTS - 1);
    const float4* xb4 = (const float4*)(xyzp + (size_t)b * NPTS * 4);
    float* bb = sBounce[w];
    float4 self = xb4[n];
    float qx = self.x, qy = self.y, qz = self.z;
    float qs = qx * qx + qy * qy + qz * qz;
    float dh[16]; int ih[16];
    #pragma unroll
    for (int j = 0; j < 16; ++j) { dh[j] = 3.4e38f; ih[j] = 0x7fffffff; }
    for (int t = 0; t < NPTS / 64; ++t) {
        int m = t * 64 + lane;
        float4 c4 = xb4[m];
        float cs = c4.x * c4.x + c4.y * c4.y + c4.z * c4.z;
        float d = qs + cs - 2.0f * (qx * c4.x + qy * c4.y + qz * c4.z);
        if (d < dh[15]) {
            dh[15] = d; ih[15] = m;
            #pragma unroll
            for (int j = 15; j >= 1; --j)
                if (dh[j] < dh[j - 1]) {
                    float td = dh[j]; dh[j] = dh[j - 1]; dh[j - 1] = td;
                    int ti = ih[j]; ih[j] = ih[j - 1]; ih[j - 1] = ti;
                }
        }
    }
    int mynb = 0;
    #pragma unroll 1
    for (int r = 0; r < KNN; ++r) {
        float d = dh[0]; int i = ih[0];
        #pragma unroll
        for (int s = 1; s < 64; s <<= 1) {
            float d2 = __shfl_xor(d, s); int i2 = __shfl_xor(i, s);
            if (d2 < d || (d2 == d && i2 < i)) { d = d2; i = i2; }
        }
        if (lane == r) mynb = i;
        if (ih[0] == i) {
            #pragma unroll
            for (int j = 0; j < 15; ++j) { dh[j] = dh[j + 1]; ih[j] = ih[j + 1]; }
            dh[15] = 3.4e38f; ih[15] = 0x7fffffff;
        }
    }
    mynb = min(max(mynb, 0), NPTS - 1);
    int quad = lane >> 4, l15 = lane & 15;
    int nb_a = __shfl(mynb, l15);
    int nbm[4];
    #pragma unroll
    for (int r = 0; r < 4; ++r) nbm[r] = __shfl(mynb, quad * 4 + r);
    const float4 xq4 = *(const float4*)(xyzp + (size_t)p * 4);
    const float4 xn4 = *(const float4*)(xyzp + ((size_t)b * NPTS + nb_a) * 4);
    float rel0 = xq4.x - xn4.x, rel1 = xq4.y - xn4.y;
    float rel2 = xq4.z - xn4.z, rel3 = xq4.w - xn4.w;
    bf8_t pe1f[2];
    #pragma unroll
    for (int s = 0; s < 2; ++s) {
        int hb = s * 32 + quad * 8;
        float W0[8], W1[8], W2[8], W3[8], Bb[8];
        *(float4*)&W0[0] = *(const float4*)(Wp1 +       hb);
        *(float4*)&W0[4] = *(const float4*)(Wp1 +       hb + 4);
        *(float4*)&W1[0] = *(const float4*)(Wp1 +  64 + hb);
        *(float4*)&W1[4] = *(const float4*)(Wp1 +  64 + hb + 4);
        *(float4*)&W2[0] = *(const float4*)(Wp1 + 128 + hb);
        *(float4*)&W2[4] = *(const float4*)(Wp1 + 128 + hb + 4);
        *(float4*)&W3[0] = *(const float4*)(Wp1 + 192 + hb);
        *(float4*)&W3[4] = *(const float4*)(Wp1 + 192 + hb + 4);
        *(float4*)&Bb[0] = *(const float4*)(bp1 + hb);
        *(float4*)&Bb[4] = *(const float4*)(bp1 + hb + 4);
        #pragma unroll
        for (int j = 0; j < 8; ++j) {
            float a = Bb[j] + rel0 * W0[j] + rel1 * W1[j]
                            + rel2 * W2[j] + rel3 * W3[j];
            pe1f[s][j] = (short)f2b(fmaxf(a, 0.f));
        }
    }
    const bf8_t* BW = (const bf8_t*)fragw;
    f4_t pe2c[4];
    #pragma unroll
    for (int t = 0; t < 4; ++t) {
        f4_t acc = {0.f, 0.f, 0.f, 0.f};
        acc = MFMA16(pe1f[0], BW[0 * 512 + (0 * 4 + t) * 64 + lane], acc);
        acc = MFMA16(pe1f[1], BW[0 * 512 + (1 * 4 + t) * 64 + lane], acc);
        float bias = bp2[t * 16 + l15];
        #pragma unroll
        for (int r = 0; r < 4; ++r) acc[r] += bias;
        pe2c[t] = acc;
    }
    f4_t ainc[4], vpec[4];
    #pragma unroll
    for (int t = 0; t < 4; ++t) {
        float qv = qw[(size_t)p * HDIM + t * 16 + l15];
        #pragma unroll
        for (int r = 0; r < 4; ++r) {
            size_t nbo = ((size_t)b * NPTS + nbm[r]) * HDIM + t * 16 + l15;
            ainc[t][r] = qv - kw[nbo] + pe2c[t][r];
            vpec[t][r] = vw[nbo] + pe2c[t][r];
        }
    }
    #pragma unroll
    for (int t = 0; t < 4; ++t)
        #pragma unroll
        for (int r = 0; r < 4; ++r)
            bb[(quad * 4 + r) * 68 + t * 16 + l15] = ainc[t][r];
    asm volatile("s_waitcnt lgkmcnt(0)" ::: "memory");
    bf8_t af[2];
    #pragma unroll
    for (int s = 0; s < 2; ++s) {
        float tmp[8];
        *(float4*)&tmp[0] = *(const float4*)&bb[l15 * 68 + s * 32 + quad * 8];
        *(float4*)&tmp[4] = *(const float4*)&bb[l15 * 68 + s * 32 + quad * 8 + 4];
        #pragma unroll
        for (int j = 0; j < 8; ++j) af[s][j] = (short)f2b(tmp[j]);
    }
    f4_t t1c[4];
    #pragma unroll
    for (int t = 0; t < 4; ++t) {
        f4_t acc = {0.f, 0.f, 0.f, 0.f};
        acc = MFMA16(af[0], BW[1 * 512 + (0 * 4 + t) * 64 + lane], acc);
        acc = MFMA16(af[1], BW[1 * 512 + (1 * 4 + t) * 64 + lane], acc);
        float bias = bt1[t * 16 + l15];
        #pragma unroll
        for (int r = 0; r < 4; ++r) t1c[t][r] = fmaxf(acc[r] + bias, 0.f);
    }
    asm volatile("s_waitcnt lgkmcnt(0)" ::: "memory");
    #pragma unroll
    for (int t = 0; t < 4; ++t)
        #pragma unroll
        for (int r = 0; r < 4; ++r)
            bb[(quad * 4 + r) * 68 + t * 16 + l15] = t1c[t][r];
    asm volatile("s_waitcnt lgkmcnt(0)" ::: "memory");
    bf8_t tf[2];
    #pragma unroll
    for (int s = 0; s < 2; ++s) {
        float tmp[8];
        *(float4*)&tmp[0] = *(const float4*)&bb[l15 * 68 + s * 32 + quad * 8];
        *(float4*)&tmp[4] = *(const float4*)&bb[l15 * 68 + s * 32 + quad * 8 + 4];
        #pragma unroll
        for (int j = 0; j < 8; ++j) tf[s][j] = (short)f2b(tmp[j]);
    }
    f4_t lgc[4];
    #pragma unroll
    for (int t = 0; t < 4; ++t) {
        f4_t acc = {0.f, 0.f, 0.f, 0.f};
        acc = MFMA16(tf[0], BW[2 * 512 + (0 * 4 + t) * 64 + lane], acc);
        acc = MFMA16(tf[1], BW[2 * 512 + (1 * 4 + t) * 64 + lane], acc);
        float bias = bt2[t * 16 + l15];
        #pragma unroll
        for (int r = 0; r < 4; ++r) lgc[t][r] = (acc[r] + bias) * 0.125f;
    }
    float res[4];
    #pragma unroll
    for (int t = 0; t < 4; ++t) {
        float m0 = fmaxf(fmaxf(lgc[t][0], lgc[t][1]), fmaxf(lgc[t][2], lgc[t][3]));
        m0 = fmaxf(m0, __shfl_xor(m0, 16));
        m0 = fmaxf(m0, __shfl_xor(m0, 32));
        float e0 = fast_exp(lgc[t][0] - m0), e1 = fast_exp(lgc[t][1] - m0);
        float e2 = fast_exp(lgc[t][2] - m0), e3 = fast_exp(lgc[t][3] - m0);
        float sl = e0 + e1 + e2 + e3;
        float rl = e0 * vpec[t][0] + e1 * vpec[t][1]
                 + e2 * vpec[t][2] + e3 * vpec[t][3];
        sl += __shfl_xor(sl, 16); sl += __shfl_xor(sl, 32);
        rl += __shfl_xor(rl, 16); rl += __shfl_xor(rl, 32);
        res[t] = rl / sl;
    }
    float rh = (quad == 0) ? res[0] : (quad == 1) ? res[1]
             : (quad == 2) ? res[2] : res[3];
    float f = features[(size_t)p * HDIM + lane];
    float o = ba[lane];
    #pragma unroll 8
    for (int c = 0; c < 64; ++c) o += __shfl(rh, c) * Wa[c * 64 + lane];
    out[(size_t)p * HDIM + lane] = o + f;
}

// ---------------------------------------------------------------------------
extern "C" void kernel_launch(void* const* d_in, const int* in_sizes, int n_in,
                              void* d_out, int out_size, void* d_ws, size_t ws_size,
                              hipStream_t stream)
{
    (void)in_sizes; (void)n_in; (void)out_size;
    const float* xyzp     = (const float*)d_in[0];
    const float* features = (const float*)d_in[1];
    const float* Wk  = (const float*)d_in[2];
    const float* bk  = (const float*)d_in[3];
    const float* Wq  = (const float*)d_in[4];
    const float* Wks = (const float*)d_in[5];
    const float* Wv  = (const float*)d_in[6];
    const float* Wp1 = (const float*)d_in[7];
    const float* bp1 = (const float*)d_in[8];
    const float* Wp2 = (const float*)d_in[9];
    const float* bp2 = (const float*)d_in[10];
    const float* Wt1 = (const float*)d_in[11];
    const float* bt1 = (const float*)d_in[12];
    const float* Wt2 = (const float*)d_in[13];
    const float* bt2 = (const float*)d_in[14];
    const float* Wa  = (const float*)d_in[15];
    const float* ba  = (const float*)d_in[16];
    float* out = (float*)d_out;
    char* ws = (char*)d_ws;

    if (ws_size >= NEED_GRID) {
        float* qw = (float*)(ws + OFF_QW);
        float* kw = (float*)(ws + OFF_KW);
        float* vw = (float*)(ws + OFF_VW);
        unsigned short* fragw = (unsigned short*)(ws + OFF_FRAG);
        int* knnIdx = (int*)(ws + OFF_KNN);
        int* ccnt   = (int*)(ws + OFF_CCNT);
        int* cstart = (int*)(ws + OFF_CSTART);
        int* cursor = (int*)(ws + OFF_CURSOR);
        int* ptIdx  = (int*)(ws + OFF_PTIDX);
        float4* ptPacked = (float4*)(ws + OFF_PTPACK);
        int* shellOff = (int*)(ws + OFF_SHELL);
        int* shellStart = shellOff + SHELL_TOT;

        prefrag_kernel<<<48, 256, 0, stream>>>(Wp2, Wt1, Wt2, fragw);
        build_shell_kernel<<<1, 64, 0, stream>>>(shellOff, shellStart);
        grid_zero_kernel<<<(2 * G3 + 255) / 256, 256, 0, stream>>>(ccnt);
        grid_count_kernel<<<(2 * NPTS) / 256, 256, 0, stream>>>(xyzp, ccnt);
        grid_scan_kernel<<<2, 256, 0, stream>>>(ccnt, cstart, cursor);
        grid_scatter_kernel<<<(2 * NPTS) / 256, 256, 0, stream>>>(
            xyzp, cursor, ptIdx, ptPacked);
        proj_kernel<<<(2 * NPTS) / 4, 256, 0, stream>>>(
            features, Wk, bk, Wq, Wks, Wv, qw, kw, vw);
        knn_grid_kernel<<<(2 * NPTS) / 4, 256, 0, stream>>>(
            xyzp, cstart, ccnt, ptIdx, ptPacked, shellOff, shellStart, knnIdx);
        LocalTransformer_80513456931527_kernel<<<(2 * NPTS) / 4, 256, 0, stream>>>(
            xyzp, features, Wp1, bp1, bp2, bt1, bt2, Wa, ba,
            qw, kw, vw, fragw, knnIdx, out);
    } else {
        // R11 proven path (ws >= 12 MB established in R11)
        float* qw = (float*)(ws + OFF_QW);
        float* kw = (float*)(ws + OFF_KW);
        float* vw = (float*)(ws + OFF_VW);
        unsigned short* fragw = (unsigned short*)(ws + OFF_FRAG);
        prefrag_kernel<<<48, 256, 0, stream>>>(Wp2, Wt1, Wt2, fragw);
        proj_kernel<<<(2 * NPTS) / 4, 256, 0, stream>>>(
            features, Wk, bk, Wq, Wks, Wv, qw, kw, vw);
        attn_knn_main_kernel<<<(2 * NPTS) / 4, 256, 0, stream>>>(
            xyzp, features, Wp1, bp1, bp2, bt1, bt2, Wa, ba,
            qw, kw, vw, fragw, out);
    }
}

// Round 13
// 418.447 us; speedup vs baseline: 2.0386x; 2.0386x over previous
//
#include <hip/hip_runtime.h>

#define NPTS 8192
#define HDIM 64
#define KNN 16
#define LOG2E 1.4426950408889634f

typedef __attribute__((ext_vector_type(8))) short bf8_t;   // 8 bf16
typedef __attribute__((ext_vector_type(4))) float f4_t;    // MFMA C/D
#define MFMA16(a, b, c) __builtin_amdgcn_mfma_f32_16x16x32_bf16(a, b, c, 0, 0, 0)

__device__ __forceinline__ float fast_exp(float x) {
    float y = x * LOG2E;
    float r;
    asm volatile("v_exp_f32 %0, %1\n\ts_nop 1" : "=v"(r) : "v"(y));
    return r;
}
__device__ __forceinline__ unsigned short f2b(float x) {   // f32 -> bf16 RNE
    unsigned v = __float_as_uint(x);
    return (unsigned short)((v + 0x7FFFu + ((v >> 16) & 1u)) >> 16);
}

// ws layout: qw 0..4MB, kw 4..8MB, vw 8..12MB, frag 12MB..+24KB
#define OFF_QW   0u
#define OFF_KW   (4u << 20)
#define OFF_VW   (8u << 20)
#define OFF_FRAG (12u << 20)

// ---------------------------------------------------------------------------
// prefrag: pack Wp2/Wt1/Wt2 into MFMA B-frag order (proven R11/R12).
// ---------------------------------------------------------------------------
__global__ void prefrag_kernel(const float* __restrict__ Wp2,
                               const float* __restrict__ Wt1,
                               const float* __restrict__ Wt2,
                               unsigned short* __restrict__ dst)
{
    int i = blockIdx.x * 256 + threadIdx.x;
    if (i >= 3 * 4096) return;
    int st = i >> 12, e = i & 4095;
    const float* W = (st == 0) ? Wp2 : (st == 1) ? Wt1 : Wt2;
    int k = e >> 6, n = e & 63;
    int s = k >> 5, quad = (k >> 3) & 3, j = k & 7;
    int t = n >> 4, l = quad * 16 + (n & 15);
    dst[st * 4096 + (s * 4 + t) * 512 + l * 8 + j] = f2b(W[e]);
}

// ---------------------------------------------------------------------------
// proj: q/k/v per point (proven R11/R12).
// ---------------------------------------------------------------------------
__global__ __launch_bounds__(256) void proj_kernel(
    const float* __restrict__ feat,
    const float* __restrict__ Wk, const float* __restrict__ bk,
    const float* __restrict__ Wq, const float* __restrict__ Wks,
    const float* __restrict__ Wv,
    float* __restrict__ qw, float* __restrict__ kw, float* __restrict__ vw)
{
    int w = threadIdx.x >> 6, lane = threadIdx.x & 63;
    int p = blockIdx.x * 4 + w;
    float f = feat[(size_t)p * HDIM + lane];
    float x = bk[lane];
    #pragma unroll 8
    for (int c = 0; c < 64; ++c) x += __shfl(f, c) * Wk[c * 64 + lane];
    float q = 0.f, k = 0.f, v = 0.f;
    #pragma unroll 8
    for (int c = 0; c < 64; ++c) {
        float xc = __shfl(x, c);
        q += xc * Wq[c * 64 + lane];
        k += xc * Wks[c * 64 + lane];
        v += xc * Wv[c * 64 + lane];
    }
    qw[(size_t)p * HDIM + lane] = q;
    kw[(size_t)p * HDIM + lane] = k;
    vw[(size_t)p * HDIM + lane] = v;
}

// ---------------------------------------------------------------------------
// main: KNN with per-lane TOP-4 + exact redo (head==4 detection), then the
// proven R11 MFMA per-neighbor MLP body. One wave per point, 4 waves/block.
// Distance expression kept VERBATIM from R10/R11 (bit-identical neighbor sets).
// ---------------------------------------------------------------------------
__global__ __launch_bounds__(256) void LocalTransformer_80513456931527_kernel(
    const float* __restrict__ xyzp, const float* __restrict__ features,
    const float* __restrict__ Wp1,  const float* __restrict__ bp1,
    const float* __restrict__ bp2,  const float* __restrict__ bt1,
    const float* __restrict__ bt2,
    const float* __restrict__ Wa,   const float* __restrict__ ba,
    const float* __restrict__ qw, const float* __restrict__ kw,
    const float* __restrict__ vw,
    const unsigned short* __restrict__ fragw,
    float* __restrict__ out)
{
    __shared__ __align__(16) float sBounce[4][16 * 68 + 4];
    int tid = threadIdx.x, w = tid >> 6, lane = tid & 63;
    int p = blockIdx.x * 4 + w;
    int b = p >> 13, n = p & (NPTS - 1);
    const float4* xb4 = (const float4*)(xyzp + (size_t)b * NPTS * 4);
    float* bb = sBounce[w];

    // ---------------- Phase 1: KNN, per-lane top-4 ----------------
    float4 self = xb4[n];
    float qx = self.x, qy = self.y, qz = self.z;
    float qs = qx * qx + qy * qy + qz * qz;

    float dh[4]; int ih[4];
    #pragma unroll
    for (int j = 0; j < 4; ++j) { dh[j] = 3.4e38f; ih[j] = 0x7fffffff; }

    for (int t = 0; t < NPTS / 64; ++t) {
        int m = t * 64 + lane;
        float4 c4 = xb4[m];
        float cs = c4.x * c4.x + c4.y * c4.y + c4.z * c4.z;
        float d = qs + cs - 2.0f * (qx * c4.x + qy * c4.y + qz * c4.z);
        if (d < dh[3]) {                // strict <: ties keep lower index
            dh[3] = d; ih[3] = m;
            #pragma unroll
            for (int j = 3; j >= 1; --j)
                if (dh[j] < dh[j - 1]) {
                    float td = dh[j]; dh[j] = dh[j - 1]; dh[j - 1] = td;
                    int ti = ih[j]; ih[j] = ih[j - 1]; ih[j - 1] = ti;
                }
        }
    }

    // merge: 16 rounds wave argmin + winner-shift; head counts consumption.
    int mynb = 0, head = 0;
    #pragma unroll 1
    for (int r = 0; r < KNN; ++r) {
        float d = dh[0]; int i = ih[0];
        #pragma unroll
        for (int s = 1; s < 64; s <<= 1) {
            float d2 = __shfl_xor(d, s); int i2 = __shfl_xor(i, s);
            if (d2 < d || (d2 == d && i2 < i)) { d = d2; i = i2; }
        }
        if (lane == r) mynb = i;
        if (ih[0] == i) {
            dh[0] = dh[1]; ih[0] = ih[1];
            dh[1] = dh[2]; ih[1] = ih[2];
            dh[2] = dh[3]; ih[2] = ih[3];
            dh[3] = 3.4e38f; ih[3] = 0x7fffffff;
            ++head;
        }
    }

    // exact repair: a lane that exhausted its 4 entries may have owned a 5th
    // member of the true top-16 -> redo this wave with the proven 16-deep scan.
    // P(trigger) ~ 0.7% of waves.
    if (__any(head >= 4)) {
        float eh[16]; int ei[16];
        #pragma unroll
        for (int j = 0; j < 16; ++j) { eh[j] = 3.4e38f; ei[j] = 0x7fffffff; }
        for (int t = 0; t < NPTS / 64; ++t) {
            int m = t * 64 + lane;
            float4 c4 = xb4[m];
            float cs = c4.x * c4.x + c4.y * c4.y + c4.z * c4.z;
            float d = qs + cs - 2.0f * (qx * c4.x + qy * c4.y + qz * c4.z);
            if (d < eh[15]) {
                eh[15] = d; ei[15] = m;
                #pragma unroll
                for (int j = 15; j >= 1; --j)
                    if (eh[j] < eh[j - 1]) {
                        float td = eh[j]; eh[j] = eh[j - 1]; eh[j - 1] = td;
                        int ti = ei[j]; ei[j] = ei[j - 1]; ei[j - 1] = ti;
                    }
            }
        }
        #pragma unroll 1
        for (int r = 0; r < KNN; ++r) {
            float d = eh[0]; int i = ei[0];
            #pragma unroll
            for (int s = 1; s < 64; s <<= 1) {
                float d2 = __shfl_xor(d, s); int i2 = __shfl_xor(i, s);
                if (d2 < d || (d2 == d && i2 < i)) { d = d2; i = i2; }
            }
            if (lane == r) mynb = i;
            if (ei[0] == i) {
                #pragma unroll
                for (int j = 0; j < 15; ++j) { eh[j] = eh[j + 1]; ei[j] = ei[j + 1]; }
                eh[15] = 3.4e38f; ei[15] = 0x7fffffff;
            }
        }
    }
    mynb = min(max(mynb, 0), NPTS - 1);

    // ---------------- Phases 2-7: proven R11 MFMA body ----------------
    int quad = lane >> 4, l15 = lane & 15;
    int nb_a = __shfl(mynb, l15);
    int nbm[4];
    #pragma unroll
    for (int r = 0; r < 4; ++r) nbm[r] = __shfl(mynb, quad * 4 + r);

    const float4 xq4 = *(const float4*)(xyzp + (size_t)p * 4);
    const float4 xn4 = *(const float4*)(xyzp + ((size_t)b * NPTS + nb_a) * 4);
    float rel0 = xq4.x - xn4.x, rel1 = xq4.y - xn4.y;
    float rel2 = xq4.z - xn4.z, rel3 = xq4.w - xn4.w;

    bf8_t pe1f[2];
    #pragma unroll
    for (int s = 0; s < 2; ++s) {
        int hb = s * 32 + quad * 8;
        float W0[8], W1[8], W2[8], W3[8], Bb[8];
        *(float4*)&W0[0] = *(const float4*)(Wp1 +       hb);
        *(float4*)&W0[4] = *(const float4*)(Wp1 +       hb + 4);
        *(float4*)&W1[0] = *(const float4*)(Wp1 +  64 + hb);
        *(float4*)&W1[4] = *(const float4*)(Wp1 +  64 + hb + 4);
        *(float4*)&W2[0] = *(const float4*)(Wp1 + 128 + hb);
        *(float4*)&W2[4] = *(const float4*)(Wp1 + 128 + hb + 4);
        *(float4*)&W3[0] = *(const float4*)(Wp1 + 192 + hb);
        *(float4*)&W3[4] = *(const float4*)(Wp1 + 192 + hb + 4);
        *(float4*)&Bb[0] = *(const float4*)(bp1 + hb);
        *(float4*)&Bb[4] = *(const float4*)(bp1 + hb + 4);
        #pragma unroll
        for (int j = 0; j < 8; ++j) {
            float a = Bb[j] + rel0 * W0[j] + rel1 * W1[j]
                            + rel2 * W2[j] + rel3 * W3[j];
            pe1f[s][j] = (short)f2b(fmaxf(a, 0.f));
        }
    }

    const bf8_t* BW = (const bf8_t*)fragw;
    f4_t pe2c[4];
    #pragma unroll
    for (int t = 0; t < 4; ++t) {
        f4_t acc = {0.f, 0.f, 0.f, 0.f};
        acc = MFMA16(pe1f[0], BW[0 * 512 + (0 * 4 + t) * 64 + lane], acc);
        acc = MFMA16(pe1f[1], BW[0 * 512 + (1 * 4 + t) * 64 + lane], acc);
        float bias = bp2[t * 16 + l15];
        #pragma unroll
        for (int r = 0; r < 4; ++r) acc[r] += bias;
        pe2c[t] = acc;
    }

    f4_t ainc[4], vpec[4];
    #pragma unroll
    for (int t = 0; t < 4; ++t) {
        float qv = qw[(size_t)p * HDIM + t * 16 + l15];
        #pragma unroll
        for (int r = 0; r < 4; ++r) {
            size_t nbo = ((size_t)b * NPTS + nbm[r]) * HDIM + t * 16 + l15;
            ainc[t][r] = qv - kw[nbo] + pe2c[t][r];
            vpec[t][r] = vw[nbo] + pe2c[t][r];
        }
    }

    #pragma unroll
    for (int t = 0; t < 4; ++t)
        #pragma unroll
        for (int r = 0; r < 4; ++r)
            bb[(quad * 4 + r) * 68 + t * 16 + l15] = ainc[t][r];
    asm volatile("s_waitcnt lgkmcnt(0)" ::: "memory");
    bf8_t af[2];
    #pragma unroll
    for (int s = 0; s < 2; ++s) {
        float tmp[8];
        *(float4*)&tmp[0] = *(const float4*)&bb[l15 * 68 + s * 32 + quad * 8];
        *(float4*)&tmp[4] = *(const float4*)&bb[l15 * 68 + s * 32 + quad * 8 + 4];
        #pragma unroll
        for (int j = 0; j < 8; ++j) af[s][j] = (short)f2b(tmp[j]);
    }

    f4_t t1c[4];
    #pragma unroll
    for (int t = 0; t < 4; ++t) {
        f4_t acc = {0.f, 0.f, 0.f, 0.f};
        acc = MFMA16(af[0], BW[1 * 512 + (0 * 4 + t) * 64 + lane], acc);
        acc = MFMA16(af[1], BW[1 * 512 + (1 * 4 + t) * 64 + lane], acc);
        float bias = bt1[t * 16 + l15];
        #pragma unroll
        for (int r = 0; r < 4; ++r) t1c[t][r] = fmaxf(acc[r] + bias, 0.f);
    }

    asm volatile("s_waitcnt lgkmcnt(0)" ::: "memory");
    #pragma unroll
    for (int t = 0; t < 4; ++t)
        #pragma unroll
        for (int r = 0; r < 4; ++r)
            bb[(quad * 4 + r) * 68 + t * 16 + l15] = t1c[t][r];
    asm volatile("s_waitcnt lgkmcnt(0)" ::: "memory");
    bf8_t tf[2];
    #pragma unroll
    for (int s = 0; s < 2; ++s) {
        float tmp[8];
        *(float4*)&tmp[0] = *(const float4*)&bb[l15 * 68 + s * 32 + quad * 8];
        *(float4*)&tmp[4] = *(const float4*)&bb[l15 * 68 + s * 32 + quad * 8 + 4];
        #pragma unroll
        for (int j = 0; j < 8; ++j) tf[s][j] = (short)f2b(tmp[j]);
    }

    f4_t lgc[4];
    #pragma unroll
    for (int t = 0; t < 4; ++t) {
        f4_t acc = {0.f, 0.f, 0.f, 0.f};
        acc = MFMA16(tf[0], BW[2 * 512 + (0 * 4 + t) * 64 + lane], acc);
        acc = MFMA16(tf[1], BW[2 * 512 + (1 * 4 + t) * 64 + lane], acc);
        float bias = bt2[t * 16 + l15];
        #pragma unroll
        for (int r = 0; r < 4; ++r) lgc[t][r] = (acc[r] + bias) * 0.125f;
    }

    float res[4];
    #pragma unroll
    for (int t = 0; t < 4; ++t) {
        float m0 = fmaxf(fmaxf(lgc[t][0], lgc[t][1]), fmaxf(lgc[t][2], lgc[t][3]));
        m0 = fmaxf(m0, __shfl_xor(m0, 16));
        m0 = fmaxf(m0, __shfl_xor(m0, 32));
        float e0 = fast_exp(lgc[t][0] - m0), e1 = fast_exp(lgc[t][1] - m0);
        float e2 = fast_exp(lgc[t][2] - m0), e3 = fast_exp(lgc[t][3] - m0);
        float sl = e0 + e1 + e2 + e3;
        float rl = e0 * vpec[t][0] + e1 * vpec[t][1]
                 + e2 * vpec[t][2] + e3 * vpec[t][3];
        sl += __shfl_xor(sl, 16); sl += __shfl_xor(sl, 32);
        rl += __shfl_xor(rl, 16); rl += __shfl_xor(rl, 32);
        res[t] = rl / sl;
    }

    float rh = (quad == 0) ? res[0] : (quad == 1) ? res[1]
             : (quad == 2) ? res[2] : res[3];
    float f = features[(size_t)p * HDIM + lane];
    float o = ba[lane];
    #pragma unroll 8
    for (int c = 0; c < 64; ++c) o += __shfl(rh, c) * Wa[c * 64 + lane];
    out[(size_t)p * HDIM + lane] = o + f;
}

// ---------------------------------------------------------------------------
extern "C" void kernel_launch(void* const* d_in, const int* in_sizes, int n_in,
                              void* d_out, int out_size, void* d_ws, size_t ws_size,
                              hipStream_t stream)
{
    (void)in_sizes; (void)n_in; (void)out_size; (void)ws_size;
    const float* xyzp     = (const float*)d_in[0];
    const float* features = (const float*)d_in[1];
    const float* Wk  = (const float*)d_in[2];
    const float* bk  = (const float*)d_in[3];
    const float* Wq  = (const float*)d_in[4];
    const float* Wks = (const float*)d_in[5];
    const float* Wv  = (const float*)d_in[6];
    const float* Wp1 = (const float*)d_in[7];
    const float* bp1 = (const float*)d_in[8];
    const float* Wp2 = (const float*)d_in[9];
    const float* bp2 = (const float*)d_in[10];
    const float* Wt1 = (const float*)d_in[11];
    const float* bt1 = (const float*)d_in[12];
    const float* Wt2 = (const float*)d_in[13];
    const float* bt2 = (const float*)d_in[14];
    const float* Wa  = (const float*)d_in[15];
    const float* ba  = (const float*)d_in[16];
    float* out = (float*)d_out;
    char* ws = (char*)d_ws;     // ws >= 14.8 MB (established R12: grid path ran)

    float* qw = (float*)(ws + OFF_QW);
    float* kw = (float*)(ws + OFF_KW);
    float* vw = (float*)(ws + OFF_VW);
    unsigned short* fragw = (unsigned short*)(ws + OFF_FRAG);

    prefrag_kernel<<<48, 256, 0, stream>>>(Wp2, Wt1, Wt2, fragw);
    proj_kernel<<<(2 * NPTS) / 4, 256, 0, stream>>>(
        features, Wk, bk, Wq, Wks, Wv, qw, kw, vw);
    LocalTransformer_80513456931527_kernel<<<(2 * NPTS) / 4, 256, 0, stream>>>(
        xyzp, features, Wp1, bp1, bp2, bt1, bt2, Wa, ba,
        qw, kw, vw, fragw, out);
}

// Round 14
// 384.002 us; speedup vs baseline: 2.2215x; 1.0897x over previous
//
#include <hip/hip_runtime.h>

#define NPTS 8192
#define HDIM 64
#define KNN 16
#define LOG2E 1.4426950408889634f

typedef __attribute__((ext_vector_type(8))) short bf8_t;   // 8 bf16
typedef __attribute__((ext_vector_type(4))) float f4_t;    // MFMA C/D
#define MFMA16(a, b, c) __builtin_amdgcn_mfma_f32_16x16x32_bf16(a, b, c, 0, 0, 0)

__device__ __forceinline__ float fast_exp(float x) {
    float y = x * LOG2E;
    float r;
    asm volatile("v_exp_f32 %0, %1\n\ts_nop 1" : "=v"(r) : "v"(y));
    return r;
}
__device__ __forceinline__ unsigned short f2b(float x) {   // f32 -> bf16 RNE
    unsigned v = __float_as_uint(x);
    return (unsigned short)((v + 0x7FFFu + ((v >> 16) & 1u)) >> 16);
}

// ws layout: qw 0..4MB, kw 4..8MB, vw 8..12MB, frag 12MB..+24KB, knnIdx +32KB..+1MB
#define OFF_QW   0u
#define OFF_KW   (4u << 20)
#define OFF_VW   (8u << 20)
#define OFF_FRAG (12u << 20)
#define OFF_KNN  ((12u << 20) + 32768u)     // 1 MB of int32; ws >= 14.8 MB (R12)

// ---------------------------------------------------------------------------
// prefrag: pack Wp2/Wt1/Wt2 into MFMA B-frag order (proven R11-R13).
// ---------------------------------------------------------------------------
__global__ void prefrag_kernel(const float* __restrict__ Wp2,
                               const float* __restrict__ Wt1,
                               const float* __restrict__ Wt2,
                               unsigned short* __restrict__ dst)
{
    int i = blockIdx.x * 256 + threadIdx.x;
    if (i >= 3 * 4096) return;
    int st = i >> 12, e = i & 4095;
    const float* W = (st == 0) ? Wp2 : (st == 1) ? Wt1 : Wt2;
    int k = e >> 6, n = e & 63;
    int s = k >> 5, quad = (k >> 3) & 3, j = k & 7;
    int t = n >> 4, l = quad * 16 + (n & 15);
    dst[st * 4096 + (s * 4 + t) * 512 + l * 8 + j] = f2b(W[e]);
}

// ---------------------------------------------------------------------------
// proj: q/k/v per point (proven R11-R13).
// ---------------------------------------------------------------------------
__global__ __launch_bounds__(256) void proj_kernel(
    const float* __restrict__ feat,
    const float* __restrict__ Wk, const float* __restrict__ bk,
    const float* __restrict__ Wq, const float* __restrict__ Wks,
    const float* __restrict__ Wv,
    float* __restrict__ qw, float* __restrict__ kw, float* __restrict__ vw)
{
    int w = threadIdx.x >> 6, lane = threadIdx.x & 63;
    int p = blockIdx.x * 4 + w;
    float f = feat[(size_t)p * HDIM + lane];
    float x = bk[lane];
    #pragma unroll 8
    for (int c = 0; c < 64; ++c) x += __shfl(f, c) * Wk[c * 64 + lane];
    float q = 0.f, k = 0.f, v = 0.f;
    #pragma unroll 8
    for (int c = 0; c < 64; ++c) {
        float xc = __shfl(x, c);
        q += xc * Wq[c * 64 + lane];
        k += xc * Wks[c * 64 + lane];
        v += xc * Wv[c * 64 + lane];
    }
    qw[(size_t)p * HDIM + lane] = q;
    kw[(size_t)p * HDIM + lane] = k;
    vw[(size_t)p * HDIM + lane] = v;
}

// ---------------------------------------------------------------------------
// knn4: 4 queries per wave — one candidate stream load serves 4 queries
// (L2 traffic /4 vs R13). Per-lane top-4 per query + R13's exact redo.
// ---------------------------------------------------------------------------
__global__ __launch_bounds__(256) void knn4_kernel(
    const float* __restrict__ xyzp, int* __restrict__ knnIdx)
{
    int w = threadIdx.x >> 6, lane = threadIdx.x & 63;
    int wid = blockIdx.x * 4 + w;            // 0..4095
    int pbase = wid * 4;                     // 4 consecutive points, same batch
    int b = pbase >> 13;
    int nbase = pbase & (NPTS - 1);
    const float4* xb4 = (const float4*)xyzp + (size_t)b * NPTS;

    float qx[4], qy[4], qz[4], qs[4];
    #pragma unroll
    for (int qi = 0; qi < 4; ++qi) {
        float4 s = xb4[nbase + qi];
        qx[qi] = s.x; qy[qi] = s.y; qz[qi] = s.z;
        qs[qi] = s.x * s.x + s.y * s.y + s.z * s.z;
    }

    float dh[4][4]; int ih[4][4];
    #pragma unroll
    for (int qi = 0; qi < 4; ++qi)
        #pragma unroll
        for (int j = 0; j < 4; ++j) { dh[qi][j] = 3.4e38f; ih[qi][j] = 0x7fffffff; }

    for (int t = 0; t < NPTS / 64; ++t) {
        int m = t * 64 + lane;
        float4 c4 = xb4[m];
        float cs = c4.x * c4.x + c4.y * c4.y + c4.z * c4.z;
        #pragma unroll
        for (int qi = 0; qi < 4; ++qi) {
            float d = qs[qi] + cs
                    - 2.0f * (qx[qi] * c4.x + qy[qi] * c4.y + qz[qi] * c4.z);
            if (d < dh[qi][3]) {             // strict <: ties keep lower index
                dh[qi][3] = d; ih[qi][3] = m;
                #pragma unroll
                for (int j = 3; j >= 1; --j)
                    if (dh[qi][j] < dh[qi][j - 1]) {
                        float td = dh[qi][j]; dh[qi][j] = dh[qi][j - 1]; dh[qi][j - 1] = td;
                        int ti = ih[qi][j]; ih[qi][j] = ih[qi][j - 1]; ih[qi][j - 1] = ti;
                    }
            }
        }
    }

    #pragma unroll
    for (int qi = 0; qi < 4; ++qi) {
        int mynb = 0, head = 0;
        #pragma unroll 1
        for (int r = 0; r < KNN; ++r) {
            float d = dh[qi][0]; int i = ih[qi][0];
            #pragma unroll
            for (int s = 1; s < 64; s <<= 1) {
                float d2 = __shfl_xor(d, s); int i2 = __shfl_xor(i, s);
                if (d2 < d || (d2 == d && i2 < i)) { d = d2; i = i2; }
            }
            if (lane == r) mynb = i;
            if (ih[qi][0] == i) {
                dh[qi][0] = dh[qi][1]; ih[qi][0] = ih[qi][1];
                dh[qi][1] = dh[qi][2]; ih[qi][1] = ih[qi][2];
                dh[qi][2] = dh[qi][3]; ih[qi][2] = ih[qi][3];
                dh[qi][3] = 3.4e38f; ih[qi][3] = 0x7fffffff;
                ++head;
            }
        }
        // exact repair (proven R13): ~0.7%/query
        if (__any(head >= 4)) {
            float eh[16]; int ei[16];
            #pragma unroll
            for (int j = 0; j < 16; ++j) { eh[j] = 3.4e38f; ei[j] = 0x7fffffff; }
            for (int t = 0; t < NPTS / 64; ++t) {
                int m = t * 64 + lane;
                float4 c4 = xb4[m];
                float cs = c4.x * c4.x + c4.y * c4.y + c4.z * c4.z;
                float d = qs[qi] + cs
                        - 2.0f * (qx[qi] * c4.x + qy[qi] * c4.y + qz[qi] * c4.z);
                if (d < eh[15]) {
                    eh[15] = d; ei[15] = m;
                    #pragma unroll
                    for (int j = 15; j >= 1; --j)
                        if (eh[j] < eh[j - 1]) {
                            float td = eh[j]; eh[j] = eh[j - 1]; eh[j - 1] = td;
                            int ti = ei[j]; ei[j] = ei[j - 1]; ei[j - 1] = ti;
                        }
                }
            }
            #pragma unroll 1
            for (int r = 0; r < KNN; ++r) {
                float d = eh[0]; int i = ei[0];
                #pragma unroll
                for (int s = 1; s < 64; s <<= 1) {
                    float d2 = __shfl_xor(d, s); int i2 = __shfl_xor(i, s);
                    if (d2 < d || (d2 == d && i2 < i)) { d = d2; i = i2; }
                }
                if (lane == r) mynb = i;
                if (ei[0] == i) {
                    #pragma unroll
                    for (int j = 0; j < 15; ++j) { eh[j] = eh[j + 1]; ei[j] = ei[j + 1]; }
                    eh[15] = 3.4e38f; ei[15] = 0x7fffffff;
                }
            }
        }
        mynb = min(max(mynb, 0), NPTS - 1);
        if (lane < KNN) knnIdx[(size_t)(pbase + qi) * KNN + lane] = mynb;
    }
}

// ---------------------------------------------------------------------------
// main: MFMA per-neighbor MLPs consuming knnIdx (proven verbatim in R12).
// ---------------------------------------------------------------------------
__global__ __launch_bounds__(256) void LocalTransformer_80513456931527_kernel(
    const float* __restrict__ xyzp, const float* __restrict__ features,
    const float* __restrict__ Wp1,  const float* __restrict__ bp1,
    const float* __restrict__ bp2,  const float* __restrict__ bt1,
    const float* __restrict__ bt2,
    const float* __restrict__ Wa,   const float* __restrict__ ba,
    const float* __restrict__ qw, const float* __restrict__ kw,
    const float* __restrict__ vw,
    const unsigned short* __restrict__ fragw,
    const int* __restrict__ knnIdx,
    float* __restrict__ out)
{
    __shared__ __align__(16) float sBounce[4][16 * 68 + 4];

    int tid = threadIdx.x, w = tid >> 6, lane = tid & 63;
    int p = blockIdx.x * 4 + w;
    int b = p >> 13;
    float* bb = sBounce[w];

    int quad = lane >> 4, l15 = lane & 15;
    int mynb = knnIdx[(size_t)p * KNN + l15];
    mynb = min(max(mynb, 0), NPTS - 1);
    int nb_a = mynb;
    int nbm[4];
    #pragma unroll
    for (int r = 0; r < 4; ++r) nbm[r] = __shfl(mynb, quad * 4 + r);

    const float4 xq4 = *(const float4*)(xyzp + (size_t)p * 4);
    const float4 xn4 = *(const float4*)(xyzp + ((size_t)b * NPTS + nb_a) * 4);
    float rel0 = xq4.x - xn4.x, rel1 = xq4.y - xn4.y;
    float rel2 = xq4.z - xn4.z, rel3 = xq4.w - xn4.w;

    bf8_t pe1f[2];
    #pragma unroll
    for (int s = 0; s < 2; ++s) {
        int hb = s * 32 + quad * 8;
        float W0[8], W1[8], W2[8], W3[8], Bb[8];
        *(float4*)&W0[0] = *(const float4*)(Wp1 +       hb);
        *(float4*)&W0[4] = *(const float4*)(Wp1 +       hb + 4);
        *(float4*)&W1[0] = *(const float4*)(Wp1 +  64 + hb);
        *(float4*)&W1[4] = *(const float4*)(Wp1 +  64 + hb + 4);
        *(float4*)&W2[0] = *(const float4*)(Wp1 + 128 + hb);
        *(float4*)&W2[4] = *(const float4*)(Wp1 + 128 + hb + 4);
        *(float4*)&W3[0] = *(const float4*)(Wp1 + 192 + hb);
        *(float4*)&W3[4] = *(const float4*)(Wp1 + 192 + hb + 4);
        *(float4*)&Bb[0] = *(const float4*)(bp1 + hb);
        *(float4*)&Bb[4] = *(const float4*)(bp1 + hb + 4);
        #pragma unroll
        for (int j = 0; j < 8; ++j) {
            float a = Bb[j] + rel0 * W0[j] + rel1 * W1[j]
                            + rel2 * W2[j] + rel3 * W3[j];
            pe1f[s][j] = (short)f2b(fmaxf(a, 0.f));
        }
    }

    const bf8_t* BW = (const bf8_t*)fragw;
    f4_t pe2c[4];
    #pragma unroll
    for (int t = 0; t < 4; ++t) {
        f4_t acc = {0.f, 0.f, 0.f, 0.f};
        acc = MFMA16(pe1f[0], BW[0 * 512 + (0 * 4 + t) * 64 + lane], acc);
        acc = MFMA16(pe1f[1], BW[0 * 512 + (1 * 4 + t) * 64 + lane], acc);
        float bias = bp2[t * 16 + l15];
        #pragma unroll
        for (int r = 0; r < 4; ++r) acc[r] += bias;
        pe2c[t] = acc;
    }

    f4_t ainc[4], vpec[4];
    #pragma unroll
    for (int t = 0; t < 4; ++t) {
        float qv = qw[(size_t)p * HDIM + t * 16 + l15];
        #pragma unroll
        for (int r = 0; r < 4; ++r) {
            size_t nbo = ((size_t)b * NPTS + nbm[r]) * HDIM + t * 16 + l15;
            ainc[t][r] = qv - kw[nbo] + pe2c[t][r];
            vpec[t][r] = vw[nbo] + pe2c[t][r];
        }
    }

    #pragma unroll
    for (int t = 0; t < 4; ++t)
        #pragma unroll
        for (int r = 0; r < 4; ++r)
            bb[(quad * 4 + r) * 68 + t * 16 + l15] = ainc[t][r];
    asm volatile("s_waitcnt lgkmcnt(0)" ::: "memory");
    bf8_t af[2];
    #pragma unroll
    for (int s = 0; s < 2; ++s) {
        float tmp[8];
        *(float4*)&tmp[0] = *(const float4*)&bb[l15 * 68 + s * 32 + quad * 8];
        *(float4*)&tmp[4] = *(const float4*)&bb[l15 * 68 + s * 32 + quad * 8 + 4];
        #pragma unroll
        for (int j = 0; j < 8; ++j) af[s][j] = (short)f2b(tmp[j]);
    }

    f4_t t1c[4];
    #pragma unroll
    for (int t = 0; t < 4; ++t) {
        f4_t acc = {0.f, 0.f, 0.f, 0.f};
        acc = MFMA16(af[0], BW[1 * 512 + (0 * 4 + t) * 64 + lane], acc);
        acc = MFMA16(af[1], BW[1 * 512 + (1 * 4 + t) * 64 + lane], acc);
        float bias = bt1[t * 16 + l15];
        #pragma unroll
        for (int r = 0; r < 4; ++r) t1c[t][r] = fmaxf(acc[r] + bias, 0.f);
    }

    asm volatile("s_waitcnt lgkmcnt(0)" ::: "memory");
    #pragma unroll
    for (int t = 0; t < 4; ++t)
        #pragma unroll
        for (int r = 0; r < 4; ++r)
            bb[(quad * 4 + r) * 68 + t * 16 + l15] = t1c[t][r];
    asm volatile("s_waitcnt lgkmcnt(0)" ::: "memory");
    bf8_t tf[2];
    #pragma unroll
    for (int s = 0; s < 2; ++s) {
        float tmp[8];
        *(float4*)&tmp[0] = *(const float4*)&bb[l15 * 68 + s * 32 + quad * 8];
        *(float4*)&tmp[4] = *(const float4*)&bb[l15 * 68 + s * 32 + quad * 8 + 4];
        #pragma unroll
        for (int j = 0; j < 8; ++j) tf[s][j] = (short)f2b(tmp[j]);
    }

    f4_t lgc[4];
    #pragma unroll
    for (int t = 0; t < 4; ++t) {
        f4_t acc = {0.f, 0.f, 0.f, 0.f};
        acc = MFMA16(tf[0], BW[2 * 512 + (0 * 4 + t) * 64 + lane], acc);
        acc = MFMA16(tf[1], BW[2 * 512 + (1 * 4 + t) * 64 + lane], acc);
        float bias = bt2[t * 16 + l15];
        #pragma unroll
        for (int r = 0; r < 4; ++r) lgc[t][r] = (acc[r] + bias) * 0.125f;
    }

    float res[4];
    #pragma unroll
    for (int t = 0; t < 4; ++t) {
        float m0 = fmaxf(fmaxf(lgc[t][0], lgc[t][1]), fmaxf(lgc[t][2], lgc[t][3]));
        m0 = fmaxf(m0, __shfl_xor(m0, 16));
        m0 = fmaxf(m0, __shfl_xor(m0, 32));
        float e0 = fast_exp(lgc[t][0] - m0), e1 = fast_exp(lgc[t][1] - m0);
        float e2 = fast_exp(lgc[t][2] - m0), e3 = fast_exp(lgc[t][3] - m0);
        float sl = e0 + e1 + e2 + e3;
        float rl = e0 * vpec[t][0] + e1 * vpec[t][1]
                 + e2 * vpec[t][2] + e3 * vpec[t][3];
        sl += __shfl_xor(sl, 16); sl += __shfl_xor(sl, 32);
        rl += __shfl_xor(rl, 16); rl += __shfl_xor(rl, 32);
        res[t] = rl / sl;
    }

    float rh = (quad == 0) ? res[0] : (quad == 1) ? res[1]
             : (quad == 2) ? res[2] : res[3];
    float f = features[(size_t)p * HDIM + lane];
    float o = ba[lane];
    #pragma unroll 8
    for (int c = 0; c < 64; ++c) o += __shfl(rh, c) * Wa[c * 64 + lane];
    out[(size_t)p * HDIM + lane] = o + f;
}

// ---------------------------------------------------------------------------
extern "C" void kernel_launch(void* const* d_in, const int* in_sizes, int n_in,
                              void* d_out, int out_size, void* d_ws, size_t ws_size,
                              hipStream_t stream)
{
    (void)in_sizes; (void)n_in; (void)out_size; (void)ws_size;
    const float* xyzp     = (const float*)d_in[0];
    const float* features = (const float*)d_in[1];
    const float* Wk  = (const float*)d_in[2];
    const float* bk  = (const float*)d_in[3];
    const float* Wq  = (const float*)d_in[4];
    const float* Wks = (const float*)d_in[5];
    const float* Wv  = (const float*)d_in[6];
    const float* Wp1 = (const float*)d_in[7];
    const float* bp1 = (const float*)d_in[8];
    const float* Wp2 = (const float*)d_in[9];
    const float* bp2 = (const float*)d_in[10];
    const float* Wt1 = (const float*)d_in[11];
    const float* bt1 = (const float*)d_in[12];
    const float* Wt2 = (const float*)d_in[13];
    const float* bt2 = (const float*)d_in[14];
    const float* Wa  = (const float*)d_in[15];
    const float* ba  = (const float*)d_in[16];
    float* out = (float*)d_out;
    char* ws = (char*)d_ws;     // ws >= 14.8 MB established (R12 grid path ran)

    float* qw = (float*)(ws + OFF_QW);
    float* kw = (float*)(ws + OFF_KW);
    float* vw = (float*)(ws + OFF_VW);
    unsigned short* fragw = (unsigned short*)(ws + OFF_FRAG);
    int* knnIdx = (int*)(ws + OFF_KNN);

    prefrag_kernel<<<48, 256, 0, stream>>>(Wp2, Wt1, Wt2, fragw);
    proj_kernel<<<(2 * NPTS) / 4, 256, 0, stream>>>(
        features, Wk, bk, Wq, Wks, Wv, qw, kw, vw);
    knn4_kernel<<<(2 * NPTS) / 16, 256, 0, stream>>>(xyzp, knnIdx);
    LocalTransformer_80513456931527_kernel<<<(2 * NPTS) / 4, 256, 0, stream>>>(
        xyzp, features, Wp1, bp1, bp2, bt1, bt2, Wa, ba,
        qw, kw, vw, fragw, knnIdx, out);
}

// Round 15
// 380.831 us; speedup vs baseline: 2.2400x; 1.0083x over previous
//
#include <hip/hip_runtime.h>

#define NPTS 8192
#define HDIM 64
#define KNN 16
#define LOG2E 1.4426950408889634f

typedef __attribute__((ext_vector_type(8))) short bf8_t;   // 8 bf16
typedef __attribute__((ext_vector_type(4))) float f4_t;    // MFMA C/D
#define MFMA16(a, b, c) __builtin_amdgcn_mfma_f32_16x16x32_bf16(a, b, c, 0, 0, 0)

__device__ __forceinline__ float fast_exp(float x) {
    float y = x * LOG2E;
    float r;
    asm volatile("v_exp_f32 %0, %1\n\ts_nop 1" : "=v"(r) : "v"(y));
    return r;
}
__device__ __forceinline__ unsigned short f2b(float x) {   // f32 -> bf16 RNE
    unsigned v = __float_as_uint(x);
    return (unsigned short)((v + 0x7FFFu + ((v >> 16) & 1u)) >> 16);
}

// ws layout: qw 0..4MB, kw 4..8MB, vw 8..12MB, frag 12MB..+24KB, knnIdx +32KB..+1MB
#define OFF_QW   0u
#define OFF_KW   (4u << 20)
#define OFF_VW   (8u << 20)
#define OFF_FRAG (12u << 20)
#define OFF_KNN  ((12u << 20) + 32768u)     // ws >= 14.8 MB (established R12)

// ---------------------------------------------------------------------------
// prefrag: pack Wp2/Wt1/Wt2 into MFMA B-frag order (proven R11-R14).
// ---------------------------------------------------------------------------
__global__ void prefrag_kernel(const float* __restrict__ Wp2,
                               const float* __restrict__ Wt1,
                               const float* __restrict__ Wt2,
                               unsigned short* __restrict__ dst)
{
    int i = blockIdx.x * 256 + threadIdx.x;
    if (i >= 3 * 4096) return;
    int st = i >> 12, e = i & 4095;
    const float* W = (st == 0) ? Wp2 : (st == 1) ? Wt1 : Wt2;
    int k = e >> 6, n = e & 63;
    int s = k >> 5, quad = (k >> 3) & 3, j = k & 7;
    int t = n >> 4, l = quad * 16 + (n & 15);
    dst[st * 4096 + (s * 4 + t) * 512 + l * 8 + j] = f2b(W[e]);
}

// ---------------------------------------------------------------------------
// proj: q/k/v per point (proven R11-R14).
// ---------------------------------------------------------------------------
__global__ __launch_bounds__(256) void proj_kernel(
    const float* __restrict__ feat,
    const float* __restrict__ Wk, const float* __restrict__ bk,
    const float* __restrict__ Wq, const float* __restrict__ Wks,
    const float* __restrict__ Wv,
    float* __restrict__ qw, float* __restrict__ kw, float* __restrict__ vw)
{
    int w = threadIdx.x >> 6, lane = threadIdx.x & 63;
    int p = blockIdx.x * 4 + w;
    float f = feat[(size_t)p * HDIM + lane];
    float x = bk[lane];
    #pragma unroll 8
    for (int c = 0; c < 64; ++c) x += __shfl(f, c) * Wk[c * 64 + lane];
    float q = 0.f, k = 0.f, v = 0.f;
    #pragma unroll 8
    for (int c = 0; c < 64; ++c) {
        float xc = __shfl(x, c);
        q += xc * Wq[c * 64 + lane];
        k += xc * Wks[c * 64 + lane];
        v += xc * Wv[c * 64 + lane];
    }
    qw[(size_t)p * HDIM + lane] = q;
    kw[(size_t)p * HDIM + lane] = k;
    vw[(size_t)p * HDIM + lane] = v;
}

// ---------------------------------------------------------------------------
// knn2: 2 queries per wave, 2048 blocks (8 blocks/CU -> 32 waves/CU cap:
// fixes R14's 26.7% occupancy). Per-lane top-4 + exact redo (proven R13/R14),
// plus an exactness-preserving wave-uniform gate tau^ = wavemax(lane minima):
// skipped values are provably > d16(final); ties pass via <=; redo ungated.
// ---------------------------------------------------------------------------
__global__ __launch_bounds__(256) void knn2_kernel(
    const float* __restrict__ xyzp, int* __restrict__ knnIdx)
{
    int w = threadIdx.x >> 6, lane = threadIdx.x & 63;
    int wid = blockIdx.x * 4 + w;            // 0..8191
    int pbase = wid * 2;                     // 2 consecutive points, same batch
    int b = pbase >> 13;
    int nbase = pbase & (NPTS - 1);
    const float4* xb4 = (const float4*)xyzp + (size_t)b * NPTS;

    float qx[2], qy[2], qz[2], qs[2], tau[2];
    #pragma unroll
    for (int qi = 0; qi < 2; ++qi) {
        float4 s = xb4[nbase + qi];
        qx[qi] = s.x; qy[qi] = s.y; qz[qi] = s.z;
        qs[qi] = s.x * s.x + s.y * s.y + s.z * s.z;
        tau[qi] = 3.4e38f;
    }

    float dh[2][4]; int ih[2][4];
    #pragma unroll
    for (int qi = 0; qi < 2; ++qi)
        #pragma unroll
        for (int j = 0; j < 4; ++j) { dh[qi][j] = 3.4e38f; ih[qi][j] = 0x7fffffff; }

    for (int t = 0; t < NPTS / 64; ++t) {
        int m = t * 64 + lane;
        float4 c4 = xb4[m];
        float cs = c4.x * c4.x + c4.y * c4.y + c4.z * c4.z;
        #pragma unroll
        for (int qi = 0; qi < 2; ++qi) {
            float d = qs[qi] + cs
                    - 2.0f * (qx[qi] * c4.x + qy[qi] * c4.y + qz[qi] * c4.z);
            if (d <= tau[qi] && d < dh[qi][3]) {   // gate + proven insert
                dh[qi][3] = d; ih[qi][3] = m;
                #pragma unroll
                for (int j = 3; j >= 1; --j)
                    if (dh[qi][j] < dh[qi][j - 1]) {
                        float td = dh[qi][j]; dh[qi][j] = dh[qi][j - 1]; dh[qi][j - 1] = td;
                        int ti = ih[qi][j]; ih[qi][j] = ih[qi][j - 1]; ih[qi][j - 1] = ti;
                    }
            }
        }
        if ((t & 15) == 15) {                      // refresh tau^ every 16 iters
            #pragma unroll
            for (int qi = 0; qi < 2; ++qi) {
                float mv = dh[qi][0];              // exact lane minimum
                #pragma unroll
                for (int s = 1; s < 64; s <<= 1) mv = fmaxf(mv, __shfl_xor(mv, s));
                tau[qi] = mv;                      // wavemax(lane minima) >= d16
            }
        }
    }

    #pragma unroll
    for (int qi = 0; qi < 2; ++qi) {
        int mynb = 0, head = 0;
        #pragma unroll 1
        for (int r = 0; r < KNN; ++r) {
            float d = dh[qi][0]; int i = ih[qi][0];
            #pragma unroll
            for (int s = 1; s < 64; s <<= 1) {
                float d2 = __shfl_xor(d, s); int i2 = __shfl_xor(i, s);
                if (d2 < d || (d2 == d && i2 < i)) { d = d2; i = i2; }
            }
            if (lane == r) mynb = i;
            if (ih[qi][0] == i) {
                dh[qi][0] = dh[qi][1]; ih[qi][0] = ih[qi][1];
                dh[qi][1] = dh[qi][2]; ih[qi][1] = ih[qi][2];
                dh[qi][2] = dh[qi][3]; ih[qi][2] = ih[qi][3];
                dh[qi][3] = 3.4e38f; ih[qi][3] = 0x7fffffff;
                ++head;
            }
        }
        // exact repair (proven R13/R14), ungated full 16-deep scan
        if (__any(head >= 4)) {
            float eh[16]; int ei[16];
            #pragma unroll
            for (int j = 0; j < 16; ++j) { eh[j] = 3.4e38f; ei[j] = 0x7fffffff; }
            for (int t = 0; t < NPTS / 64; ++t) {
                int m = t * 64 + lane;
                float4 c4 = xb4[m];
                float cs = c4.x * c4.x + c4.y * c4.y + c4.z * c4.z;
                float d = qs[qi] + cs
                        - 2.0f * (qx[qi] * c4.x + qy[qi] * c4.y + qz[qi] * c4.z);
                if (d < eh[15]) {
                    eh[15] = d; ei[15] = m;
                    #pragma unroll
                    for (int j = 15; j >= 1; --j)
                        if (eh[j] < eh[j - 1]) {
                            float td = eh[j]; eh[j] = eh[j - 1]; eh[j - 1] = td;
                            int ti = ei[j]; ei[j] = ei[j - 1]; ei[j - 1] = ti;
                        }
                }
            }
            #pragma unroll 1
            for (int r = 0; r < KNN; ++r) {
                float d = eh[0]; int i = ei[0];
                #pragma unroll
                for (int s = 1; s < 64; s <<= 1) {
                    float d2 = __shfl_xor(d, s); int i2 = __shfl_xor(i, s);
                    if (d2 < d || (d2 == d && i2 < i)) { d = d2; i = i2; }
                }
                if (lane == r) mynb = i;
                if (ei[0] == i) {
                    #pragma unroll
                    for (int j = 0; j < 15; ++j) { eh[j] = eh[j + 1]; ei[j] = ei[j + 1]; }
                    eh[15] = 3.4e38f; ei[15] = 0x7fffffff;
                }
            }
        }
        mynb = min(max(mynb, 0), NPTS - 1);
        if (lane < KNN) knnIdx[(size_t)(pbase + qi) * KNN + lane] = mynb;
    }
}

// ---------------------------------------------------------------------------
// main: MFMA per-neighbor MLPs consuming knnIdx (proven verbatim R12/R14).
// ---------------------------------------------------------------------------
__global__ __launch_bounds__(256) void LocalTransformer_80513456931527_kernel(
    const float* __restrict__ xyzp, const float* __restrict__ features,
    const float* __restrict__ Wp1,  const float* __restrict__ bp1,
    const float* __restrict__ bp2,  const float* __restrict__ bt1,
    const float* __restrict__ bt2,
    const float* __restrict__ Wa,   const float* __restrict__ ba,
    const float* __restrict__ qw, const float* __restrict__ kw,
    const float* __restrict__ vw,
    const unsigned short* __restrict__ fragw,
    const int* __restrict__ knnIdx,
    float* __restrict__ out)
{
    __shared__ __align__(16) float sBounce[4][16 * 68 + 4];

    int tid = threadIdx.x, w = tid >> 6, lane = tid & 63;
    int p = blockIdx.x * 4 + w;
    int b = p >> 13;
    float* bb = sBounce[w];

    int quad = lane >> 4, l15 = lane & 15;
    int mynb = knnIdx[(size_t)p * KNN + l15];
    mynb = min(max(mynb, 0), NPTS - 1);
    int nb_a = mynb;
    int nbm[4];
    #pragma unroll
    for (int r = 0; r < 4; ++r) nbm[r] = __shfl(mynb, quad * 4 + r);

    const float4 xq4 = *(const float4*)(xyzp + (size_t)p * 4);
    const float4 xn4 = *(const float4*)(xyzp + ((size_t)b * NPTS + nb_a) * 4);
    float rel0 = xq4.x - xn4.x, rel1 = xq4.y - xn4.y;
    float rel2 = xq4.z - xn4.z, rel3 = xq4.w - xn4.w;

    bf8_t pe1f[2];
    #pragma unroll
    for (int s = 0; s < 2; ++s) {
        int hb = s * 32 + quad * 8;
        float W0[8], W1[8], W2[8], W3[8], Bb[8];
        *(float4*)&W0[0] = *(const float4*)(Wp1 +       hb);
        *(float4*)&W0[4] = *(const float4*)(Wp1 +       hb + 4);
        *(float4*)&W1[0] = *(const float4*)(Wp1 +  64 + hb);
        *(float4*)&W1[4] = *(const float4*)(Wp1 +  64 + hb + 4);
        *(float4*)&W2[0] = *(const float4*)(Wp1 + 128 + hb);
        *(float4*)&W2[4] = *(const float4*)(Wp1 + 128 + hb + 4);
        *(float4*)&W3[0] = *(const float4*)(Wp1 + 192 + hb);
        *(float4*)&W3[4] = *(const float4*)(Wp1 + 192 + hb + 4);
        *(float4*)&Bb[0] = *(const float4*)(bp1 + hb);
        *(float4*)&Bb[4] = *(const float4*)(bp1 + hb + 4);
        #pragma unroll
        for (int j = 0; j < 8; ++j) {
            float a = Bb[j] + rel0 * W0[j] + rel1 * W1[j]
                            + rel2 * W2[j] + rel3 * W3[j];
            pe1f[s][j] = (short)f2b(fmaxf(a, 0.f));
        }
    }

    const bf8_t* BW = (const bf8_t*)fragw;
    f4_t pe2c[4];
    #pragma unroll
    for (int t = 0; t < 4; ++t) {
        f4_t acc = {0.f, 0.f, 0.f, 0.f};
        acc = MFMA16(pe1f[0], BW[0 * 512 + (0 * 4 + t) * 64 + lane], acc);
        acc = MFMA16(pe1f[1], BW[0 * 512 + (1 * 4 + t) * 64 + lane], acc);
        float bias = bp2[t * 16 + l15];
        #pragma unroll
        for (int r = 0; r < 4; ++r) acc[r] += bias;
        pe2c[t] = acc;
    }

    f4_t ainc[4], vpec[4];
    #pragma unroll
    for (int t = 0; t < 4; ++t) {
        float qv = qw[(size_t)p * HDIM + t * 16 + l15];
        #pragma unroll
        for (int r = 0; r < 4; ++r) {
            size_t nbo = ((size_t)b * NPTS + nbm[r]) * HDIM + t * 16 + l15;
            ainc[t][r] = qv - kw[nbo] + pe2c[t][r];
            vpec[t][r] = vw[nbo] + pe2c[t][r];
        }
    }

    #pragma unroll
    for (int t = 0; t < 4; ++t)
        #pragma unroll
        for (int r = 0; r < 4; ++r)
            bb[(quad * 4 + r) * 68 + t * 16 + l15] = ainc[t][r];
    asm volatile("s_waitcnt lgkmcnt(0)" ::: "memory");
    bf8_t af[2];
    #pragma unroll
    for (int s = 0; s < 2; ++s) {
        float tmp[8];
        *(float4*)&tmp[0] = *(const float4*)&bb[l15 * 68 + s * 32 + quad * 8];
        *(float4*)&tmp[4] = *(const float4*)&bb[l15 * 68 + s * 32 + quad * 8 + 4];
        #pragma unroll
        for (int j = 0; j < 8; ++j) af[s][j] = (short)f2b(tmp[j]);
    }

    f4_t t1c[4];
    #pragma unroll
    for (int t = 0; t < 4; ++t) {
        f4_t acc = {0.f, 0.f, 0.f, 0.f};
        acc = MFMA16(af[0], BW[1 * 512 + (0 * 4 + t) * 64 + lane], acc);
        acc = MFMA16(af[1], BW[1 * 512 + (1 * 4 + t) * 64 + lane], acc);
        float bias = bt1[t * 16 + l15];
        #pragma unroll
        for (int r = 0; r < 4; ++r) t1c[t][r] = fmaxf(acc[r] + bias, 0.f);
    }

    asm volatile("s_waitcnt lgkmcnt(0)" ::: "memory");
    #pragma unroll
    for (int t = 0; t < 4; ++t)
        #pragma unroll
        for (int r = 0; r < 4; ++r)
            bb[(quad * 4 + r) * 68 + t * 16 + l15] = t1c[t][r];
    asm volatile("s_waitcnt lgkmcnt(0)" ::: "memory");
    bf8_t tf[2];
    #pragma unroll
    for (int s = 0; s < 2; ++s) {
        float tmp[8];
        *(float4*)&tmp[0] = *(const float4*)&bb[l15 * 68 + s * 32 + quad * 8];
        *(float4*)&tmp[4] = *(const float4*)&bb[l15 * 68 + s * 32 + quad * 8 + 4];
        #pragma unroll
        for (int j = 0; j < 8; ++j) tf[s][j] = (short)f2b(tmp[j]);
    }

    f4_t lgc[4];
    #pragma unroll
    for (int t = 0; t < 4; ++t) {
        f4_t acc = {0.f, 0.f, 0.f, 0.f};
        acc = MFMA16(tf[0], BW[2 * 512 + (0 * 4 + t) * 64 + lane], acc);
        acc = MFMA16(tf[1], BW[2 * 512 + (1 * 4 + t) * 64 + lane], acc);
        float bias = bt2[t * 16 + l15];
        #pragma unroll
        for (int r = 0; r < 4; ++r) lgc[t][r] = (acc[r] + bias) * 0.125f;
    }

    float res[4];
    #pragma unroll
    for (int t = 0; t < 4; ++t) {
        float m0 = fmaxf(fmaxf(lgc[t][0], lgc[t][1]), fmaxf(lgc[t][2], lgc[t][3]));
        m0 = fmaxf(m0, __shfl_xor(m0, 16));
        m0 = fmaxf(m0, __shfl_xor(m0, 32));
        float e0 = fast_exp(lgc[t][0] - m0), e1 = fast_exp(lgc[t][1] - m0);
        float e2 = fast_exp(lgc[t][2] - m0), e3 = fast_exp(lgc[t][3] - m0);
        float sl = e0 + e1 + e2 + e3;
        float rl = e0 * vpec[t][0] + e1 * vpec[t][1]
                 + e2 * vpec[t][2] + e3 * vpec[t][3];
        sl += __shfl_xor(sl, 16); sl += __shfl_xor(sl, 32);
        rl += __shfl_xor(rl, 16); rl += __shfl_xor(rl, 32);
        res[t] = rl / sl;
    }

    float rh = (quad == 0) ? res[0] : (quad == 1) ? res[1]
             : (quad == 2) ? res[2] : res[3];
    float f = features[(size_t)p * HDIM + lane];
    float o = ba[lane];
    #pragma unroll 8
    for (int c = 0; c < 64; ++c) o += __shfl(rh, c) * Wa[c * 64 + lane];
    out[(size_t)p * HDIM + lane] = o + f;
}

// ---------------------------------------------------------------------------
extern "C" void kernel_launch(void* const* d_in, const int* in_sizes, int n_in,
                              void* d_out, int out_size, void* d_ws, size_t ws_size,
                              hipStream_t stream)
{
    (void)in_sizes; (void)n_in; (void)out_size; (void)ws_size;
    const float* xyzp     = (const float*)d_in[0];
    const float* features = (const float*)d_in[1];
    const float* Wk  = (const float*)d_in[2];
    const float* bk  = (const float*)d_in[3];
    const float* Wq  = (const float*)d_in[4];
    const float* Wks = (const float*)d_in[5];
    const float* Wv  = (const float*)d_in[6];
    const float* Wp1 = (const float*)d_in[7];
    const float* bp1 = (const float*)d_in[8];
    const float* Wp2 = (const float*)d_in[9];
    const float* bp2 = (const float*)d_in[10];
    const float* Wt1 = (const float*)d_in[11];
    const float* bt1 = (const float*)d_in[12];
    const float* Wt2 = (const float*)d_in[13];
    const float* bt2 = (const float*)d_in[14];
    const float* Wa  = (const float*)d_in[15];
    const float* ba  = (const float*)d_in[16];
    float* out = (float*)d_out;
    char* ws = (char*)d_ws;

    float* qw = (float*)(ws + OFF_QW);
    float* kw = (float*)(ws + OFF_KW);
    float* vw = (float*)(ws + OFF_VW);
    unsigned short* fragw = (unsigned short*)(ws + OFF_FRAG);
    int* knnIdx = (int*)(ws + OFF_KNN);

    prefrag_kernel<<<48, 256, 0, stream>>>(Wp2, Wt1, Wt2, fragw);
    proj_kernel<<<(2 * NPTS) / 4, 256, 0, stream>>>(
        features, Wk, bk, Wq, Wks, Wv, qw, kw, vw);
    knn2_kernel<<<(2 * NPTS) / 8, 256, 0, stream>>>(xyzp, knnIdx);
    LocalTransformer_80513456931527_kernel<<<(2 * NPTS) / 4, 256, 0, stream>>>(
        xyzp, features, Wp1, bp1, bp2, bt1, bt2, Wa, ba,
        qw, kw, vw, fragw, knnIdx, out);
}

// Round 16
// 374.962 us; speedup vs baseline: 2.2750x; 1.0157x over previous
//
#include <hip/hip_runtime.h>

#define NPTS 8192
#define HDIM 64
#define KNN 16
#define LOG2E 1.4426950408889634f

typedef __attribute__((ext_vector_type(8))) short bf8_t;   // 8 bf16
typedef __attribute__((ext_vector_type(4))) float f4_t;    // MFMA C/D
#define MFMA16(a, b, c) __builtin_amdgcn_mfma_f32_16x16x32_bf16(a, b, c, 0, 0, 0)

__device__ __forceinline__ float fast_exp(float x) {
    float y = x * LOG2E;
    float r;
    asm volatile("v_exp_f32 %0, %1\n\ts_nop 1" : "=v"(r) : "v"(y));
    return r;
}
__device__ __forceinline__ unsigned short f2b(float x) {   // f32 -> bf16 RNE
    unsigned v = __float_as_uint(x);
    return (unsigned short)((v + 0x7FFFu + ((v >> 16) & 1u)) >> 16);
}

// ws layout: qw 0..4MB, kw 4..8MB, vw 8..12MB, frag 12MB..+24KB, knnIdx +32KB..+1MB
#define OFF_QW   0u
#define OFF_KW   (4u << 20)
#define OFF_VW   (8u << 20)
#define OFF_FRAG (12u << 20)
#define OFF_KNN  ((12u << 20) + 32768u)     // ws >= 14.8 MB (established R12)

// ---------------------------------------------------------------------------
// prefrag: pack Wp2/Wt1/Wt2 into MFMA B-frag order (proven R11-R15).
// ---------------------------------------------------------------------------
__global__ void prefrag_kernel(const float* __restrict__ Wp2,
                               const float* __restrict__ Wt1,
                               const float* __restrict__ Wt2,
                               unsigned short* __restrict__ dst)
{
    int i = blockIdx.x * 256 + threadIdx.x;
    if (i >= 3 * 4096) return;
    int st = i >> 12, e = i & 4095;
    const float* W = (st == 0) ? Wp2 : (st == 1) ? Wt1 : Wt2;
    int k = e >> 6, n = e & 63;
    int s = k >> 5, quad = (k >> 3) & 3, j = k & 7;
    int t = n >> 4, l = quad * 16 + (n & 15);
    dst[st * 4096 + (s * 4 + t) * 512 + l * 8 + j] = f2b(W[e]);
}

// ---------------------------------------------------------------------------
// proj v2: LDS-staged weights. R14's proj re-read 64 KB of W per wave from
// L2 (~1 GB total -> L2-BW-bound at ~23 TB/s = the whole 45 us). 1024-thread
// blocks stage all 4 matrices once (64 KB, 2 blocks/CU) -> W traffic /16.
// Inner math bit-identical to R14 (f32 everywhere).
// ---------------------------------------------------------------------------
__global__ __launch_bounds__(1024) void proj_kernel(
    const float* __restrict__ feat,
    const float* __restrict__ Wk, const float* __restrict__ bk,
    const float* __restrict__ Wq, const float* __restrict__ Wks,
    const float* __restrict__ Wv,
    float* __restrict__ qw, float* __restrict__ kw, float* __restrict__ vw)
{
    __shared__ __align__(16) float4 sW[4][1024];   // Wk, Wq, Wks, Wv (64 KB)
    int tid = threadIdx.x;
    sW[0][tid] = ((const float4*)Wk)[tid];
    sW[1][tid] = ((const float4*)Wq)[tid];
    sW[2][tid] = ((const float4*)Wks)[tid];
    sW[3][tid] = ((const float4*)Wv)[tid];
    __syncthreads();
    const float* sWk  = (const float*)sW[0];
    const float* sWq  = (const float*)sW[1];
    const float* sWks = (const float*)sW[2];
    const float* sWv  = (const float*)sW[3];

    int w = tid >> 6, lane = tid & 63;
    int p = blockIdx.x * 16 + w;
    float f = feat[(size_t)p * HDIM + lane];
    float x = bk[lane];
    #pragma unroll 8
    for (int c = 0; c < 64; ++c) x += __shfl(f, c) * sWk[c * 64 + lane];
    float q = 0.f, k = 0.f, v = 0.f;
    #pragma unroll 8
    for (int c = 0; c < 64; ++c) {
        float xc = __shfl(x, c);
        q += xc * sWq[c * 64 + lane];
        k += xc * sWks[c * 64 + lane];
        v += xc * sWv[c * 64 + lane];
    }
    qw[(size_t)p * HDIM + lane] = q;
    kw[(size_t)p * HDIM + lane] = k;
    vw[(size_t)p * HDIM + lane] = v;
}

// ---------------------------------------------------------------------------
// knn4_ilp: R14's proven knn4 (4 queries/wave, top-4 + exact redo), with the
// scan restructured as 32 iters x 4 independent loads hoisted ahead of the
// insert bodies -> 4 outstanding L2 loads/wave (latency amortized 4x).
// Candidate partition differs from R14; final top-16 set provably identical.
// ---------------------------------------------------------------------------
__global__ __launch_bounds__(256) void knn4_kernel(
    const float* __restrict__ xyzp, int* __restrict__ knnIdx)
{
    int w = threadIdx.x >> 6, lane = threadIdx.x & 63;
    int wid = blockIdx.x * 4 + w;            // 0..4095
    int pbase = wid * 4;                     // 4 consecutive points, same batch
    int b = pbase >> 13;
    int nbase = pbase & (NPTS - 1);
    const float4* xb4 = (const float4*)xyzp + (size_t)b * NPTS;

    float qx[4], qy[4], qz[4], qs[4];
    #pragma unroll
    for (int qi = 0; qi < 4; ++qi) {
        float4 s = xb4[nbase + qi];
        qx[qi] = s.x; qy[qi] = s.y; qz[qi] = s.z;
        qs[qi] = s.x * s.x + s.y * s.y + s.z * s.z;
    }

    float dh[4][4]; int ih[4][4];
    #pragma unroll
    for (int qi = 0; qi < 4; ++qi)
        #pragma unroll
        for (int j = 0; j < 4; ++j) { dh[qi][j] = 3.4e38f; ih[qi][j] = 0x7fffffff; }

    for (int t = 0; t < NPTS / 256; ++t) {           // 32 iters x 4 loads
        float4 c[4];
        #pragma unroll
        for (int u = 0; u < 4; ++u)
            c[u] = xb4[(t * 4 + u) * 64 + lane];     // 4 independent loads
        #pragma unroll
        for (int u = 0; u < 4; ++u) {
            int m = (t * 4 + u) * 64 + lane;
            float cs = c[u].x * c[u].x + c[u].y * c[u].y + c[u].z * c[u].z;
            #pragma unroll
            for (int qi = 0; qi < 4; ++qi) {
                float d = qs[qi] + cs
                        - 2.0f * (qx[qi] * c[u].x + qy[qi] * c[u].y + qz[qi] * c[u].z);
                if (d < dh[qi][3]) {     // strict <: ties keep lower index
                    dh[qi][3] = d; ih[qi][3] = m;
                    #pragma unroll
                    for (int j = 3; j >= 1; --j)
                        if (dh[qi][j] < dh[qi][j - 1]) {
                            float td = dh[qi][j]; dh[qi][j] = dh[qi][j - 1]; dh[qi][j - 1] = td;
                            int ti = ih[qi][j]; ih[qi][j] = ih[qi][j - 1]; ih[qi][j - 1] = ti;
                        }
                }
            }
        }
    }

    #pragma unroll
    for (int qi = 0; qi < 4; ++qi) {
        int mynb = 0, head = 0;
        #pragma unroll 1
        for (int r = 0; r < KNN; ++r) {
            float d = dh[qi][0]; int i = ih[qi][0];
            #pragma unroll
            for (int s = 1; s < 64; s <<= 1) {
                float d2 = __shfl_xor(d, s); int i2 = __shfl_xor(i, s);
                if (d2 < d || (d2 == d && i2 < i)) { d = d2; i = i2; }
            }
            if (lane == r) mynb = i;
            if (ih[qi][0] == i) {
                dh[qi][0] = dh[qi][1]; ih[qi][0] = ih[qi][1];
                dh[qi][1] = dh[qi][2]; ih[qi][1] = ih[qi][2];
                dh[qi][2] = dh[qi][3]; ih[qi][2] = ih[qi][3];
                dh[qi][3] = 3.4e38f; ih[qi][3] = 0x7fffffff;
                ++head;
            }
        }
        // exact repair (proven R13-R15): ~0.7%/query
        if (__any(head >= 4)) {
            float eh[16]; int ei[16];
            #pragma unroll
            for (int j = 0; j < 16; ++j) { eh[j] = 3.4e38f; ei[j] = 0x7fffffff; }
            for (int t = 0; t < NPTS / 64; ++t) {
                int m = t * 64 + lane;
                float4 c4 = xb4[m];
                float cs = c4.x * c4.x + c4.y * c4.y + c4.z * c4.z;
                float d = qs[qi] + cs
                        - 2.0f * (qx[qi] * c4.x + qy[qi] * c4.y + qz[qi] * c4.z);
                if (d < eh[15]) {
                    eh[15] = d; ei[15] = m;
                    #pragma unroll
                    for (int j = 15; j >= 1; --j)
                        if (eh[j] < eh[j - 1]) {
                            float td = eh[j]; eh[j] = eh[j - 1]; eh[j - 1] = td;
                            int ti = ei[j]; ei[j] = ei[j - 1]; ei[j - 1] = ti;
                        }
                }
            }
            #pragma unroll 1
            for (int r = 0; r < KNN; ++r) {
                float d = eh[0]; int i = ei[0];
                #pragma unroll
                for (int s = 1; s < 64; s <<= 1) {
                    float d2 = __shfl_xor(d, s); int i2 = __shfl_xor(i, s);
                    if (d2 < d || (d2 == d && i2 < i)) { d = d2; i = i2; }
                }
                if (lane == r) mynb = i;
                if (ei[0] == i) {
                    #pragma unroll
                    for (int j = 0; j < 15; ++j) { eh[j] = eh[j + 1]; ei[j] = ei[j + 1]; }
                    eh[15] = 3.4e38f; ei[15] = 0x7fffffff;
                }
            }
        }
        mynb = min(max(mynb, 0), NPTS - 1);
        if (lane < KNN) knnIdx[(size_t)(pbase + qi) * KNN + lane] = mynb;
    }
}

// ---------------------------------------------------------------------------
// main: MFMA per-neighbor MLPs consuming knnIdx (proven verbatim R12/R14/R15).
// ---------------------------------------------------------------------------
__global__ __launch_bounds__(256) void LocalTransformer_80513456931527_kernel(
    const float* __restrict__ xyzp, const float* __restrict__ features,
    const float* __restrict__ Wp1,  const float* __restrict__ bp1,
    const float* __restrict__ bp2,  const float* __restrict__ bt1,
    const float* __restrict__ bt2,
    const float* __restrict__ Wa,   const float* __restrict__ ba,
    const float* __restrict__ qw, const float* __restrict__ kw,
    const float* __restrict__ vw,
    const unsigned short* __restrict__ fragw,
    const int* __restrict__ knnIdx,
    float* __restrict__ out)
{
    __shared__ __align__(16) float sBounce[4][16 * 68 + 4];

    int tid = threadIdx.x, w = tid >> 6, lane = tid & 63;
    int p = blockIdx.x * 4 + w;
    int b = p >> 13;
    float* bb = sBounce[w];

    int quad = lane >> 4, l15 = lane & 15;
    int mynb = knnIdx[(size_t)p * KNN + l15];
    mynb = min(max(mynb, 0), NPTS - 1);
    int nb_a = mynb;
    int nbm[4];
    #pragma unroll
    for (int r = 0; r < 4; ++r) nbm[r] = __shfl(mynb, quad * 4 + r);

    const float4 xq4 = *(const float4*)(xyzp + (size_t)p * 4);
    const float4 xn4 = *(const float4*)(xyzp + ((size_t)b * NPTS + nb_a) * 4);
    float rel0 = xq4.x - xn4.x, rel1 = xq4.y - xn4.y;
    float rel2 = xq4.z - xn4.z, rel3 = xq4.w - xn4.w;

    bf8_t pe1f[2];
    #pragma unroll
    for (int s = 0; s < 2; ++s) {
        int hb = s * 32 + quad * 8;
        float W0[8], W1[8], W2[8], W3[8], Bb[8];
        *(float4*)&W0[0] = *(const float4*)(Wp1 +       hb);
        *(float4*)&W0[4] = *(const float4*)(Wp1 +       hb + 4);
        *(float4*)&W1[0] = *(const float4*)(Wp1 +  64 + hb);
        *(float4*)&W1[4] = *(const float4*)(Wp1 +  64 + hb + 4);
        *(float4*)&W2[0] = *(const float4*)(Wp1 + 128 + hb);
        *(float4*)&W2[4] = *(const float4*)(Wp1 + 128 + hb + 4);
        *(float4*)&W3[0] = *(const float4*)(Wp1 + 192 + hb);
        *(float4*)&W3[4] = *(const float4*)(Wp1 + 192 + hb + 4);
        *(float4*)&Bb[0] = *(const float4*)(bp1 + hb);
        *(float4*)&Bb[4] = *(const float4*)(bp1 + hb + 4);
        #pragma unroll
        for (int j = 0; j < 8; ++j) {
            float a = Bb[j] + rel0 * W0[j] + rel1 * W1[j]
                            + rel2 * W2[j] + rel3 * W3[j];
            pe1f[s][j] = (short)f2b(fmaxf(a, 0.f));
        }
    }

    const bf8_t* BW = (const bf8_t*)fragw;
    f4_t pe2c[4];
    #pragma unroll
    for (int t = 0; t < 4; ++t) {
        f4_t acc = {0.f, 0.f, 0.f, 0.f};
        acc = MFMA16(pe1f[0], BW[0 * 512 + (0 * 4 + t) * 64 + lane], acc);
        acc = MFMA16(pe1f[1], BW[0 * 512 + (1 * 4 + t) * 64 + lane], acc);
        float bias = bp2[t * 16 + l15];
        #pragma unroll
        for (int r = 0; r < 4; ++r) acc[r] += bias;
        pe2c[t] = acc;
    }

    f4_t ainc[4], vpec[4];
    #pragma unroll
    for (int t = 0; t < 4; ++t) {
        float qv = qw[(size_t)p * HDIM + t * 16 + l15];
        #pragma unroll
        for (int r = 0; r < 4; ++r) {
            size_t nbo = ((size_t)b * NPTS + nbm[r]) * HDIM + t * 16 + l15;
            ainc[t][r] = qv - kw[nbo] + pe2c[t][r];
            vpec[t][r] = vw[nbo] + pe2c[t][r];
        }
    }

    #pragma unroll
    for (int t = 0; t < 4; ++t)
        #pragma unroll
        for (int r = 0; r < 4; ++r)
            bb[(quad * 4 + r) * 68 + t * 16 + l15] = ainc[t][r];
    asm volatile("s_waitcnt lgkmcnt(0)" ::: "memory");
    bf8_t af[2];
    #pragma unroll
    for (int s = 0; s < 2; ++s) {
        float tmp[8];
        *(float4*)&tmp[0] = *(const float4*)&bb[l15 * 68 + s * 32 + quad * 8];
        *(float4*)&tmp[4] = *(const float4*)&bb[l15 * 68 + s * 32 + quad * 8 + 4];
        #pragma unroll
        for (int j = 0; j < 8; ++j) af[s][j] = (short)f2b(tmp[j]);
    }

    f4_t t1c[4];
    #pragma unroll
    for (int t = 0; t < 4; ++t) {
        f4_t acc = {0.f, 0.f, 0.f, 0.f};
        acc = MFMA16(af[0], BW[1 * 512 + (0 * 4 + t) * 64 + lane], acc);
        acc = MFMA16(af[1], BW[1 * 512 + (1 * 4 + t) * 64 + lane], acc);
        float bias = bt1[t * 16 + l15];
        #pragma unroll
        for (int r = 0; r < 4; ++r) t1c[t][r] = fmaxf(acc[r] + bias, 0.f);
    }

    asm volatile("s_waitcnt lgkmcnt(0)" ::: "memory");
    #pragma unroll
    for (int t = 0; t < 4; ++t)
        #pragma unroll
        for (int r = 0; r < 4; ++r)
            bb[(quad * 4 + r) * 68 + t * 16 + l15] = t1c[t][r];
    asm volatile("s_waitcnt lgkmcnt(0)" ::: "memory");
    bf8_t tf[2];
    #pragma unroll
    for (int s = 0; s < 2; ++s) {
        float tmp[8];
        *(float4*)&tmp[0] = *(const float4*)&bb[l15 * 68 + s * 32 + quad * 8];
        *(float4*)&tmp[4] = *(const float4*)&bb[l15 * 68 + s * 32 + quad * 8 + 4];
        #pragma unroll
        for (int j = 0; j < 8; ++j) tf[s][j] = (short)f2b(tmp[j]);
    }

    f4_t lgc[4];
    #pragma unroll
    for (int t = 0; t < 4; ++t) {
        f4_t acc = {0.f, 0.f, 0.f, 0.f};
        acc = MFMA16(tf[0], BW[2 * 512 + (0 * 4 + t) * 64 + lane], acc);
        acc = MFMA16(tf[1], BW[2 * 512 + (1 * 4 + t) * 64 + lane], acc);
        float bias = bt2[t * 16 + l15];
        #pragma unroll
        for (int r = 0; r < 4; ++r) lgc[t][r] = (acc[r] + bias) * 0.125f;
    }

    float res[4];
    #pragma unroll
    for (int t = 0; t < 4; ++t) {
        float m0 = fmaxf(fmaxf(lgc[t][0], lgc[t][1]), fmaxf(lgc[t][2], lgc[t][3]));
        m0 = fmaxf(m0, __shfl_xor(m0, 16));
        m0 = fmaxf(m0, __shfl_xor(m0, 32));
        float e0 = fast_exp(lgc[t][0] - m0), e1 = fast_exp(lgc[t][1] - m0);
        float e2 = fast_exp(lgc[t][2] - m0), e3 = fast_exp(lgc[t][3] - m0);
        float sl = e0 + e1 + e2 + e3;
        float rl = e0 * vpec[t][0] + e1 * vpec[t][1]
                 + e2 * vpec[t][2] + e3 * vpec[t][3];
        sl += __shfl_xor(sl, 16); sl += __shfl_xor(sl, 32);
        rl += __shfl_xor(rl, 16); rl += __shfl_xor(rl, 32);
        res[t] = rl / sl;
    }

    float rh = (quad == 0) ? res[0] : (quad == 1) ? res[1]
             : (quad == 2) ? res[2] : res[3];
    float f = features[(size_t)p * HDIM + lane];
    float o = ba[lane];
    #pragma unroll 8
    for (int c = 0; c < 64; ++c) o += __shfl(rh, c) * Wa[c * 64 + lane];
    out[(size_t)p * HDIM + lane] = o + f;
}

// ---------------------------------------------------------------------------
extern "C" void kernel_launch(void* const* d_in, const int* in_sizes, int n_in,
                              void* d_out, int out_size, void* d_ws, size_t ws_size,
                              hipStream_t stream)
{
    (void)in_sizes; (void)n_in; (void)out_size; (void)ws_size;
    const float* xyzp     = (const float*)d_in[0];
    const float* features = (const float*)d_in[1];
    const float* Wk  = (const float*)d_in[2];
    const float* bk  = (const float*)d_in[3];
    const float* Wq  = (const float*)d_in[4];
    const float* Wks = (const float*)d_in[5];
    const float* Wv  = (const float*)d_in[6];
    const float* Wp1 = (const float*)d_in[7];
    const float* bp1 = (const float*)d_in[8];
    const float* Wp2 = (const float*)d_in[9];
    const float* bp2 = (const float*)d_in[10];
    const float* Wt1 = (const float*)d_in[11];
    const float* bt1 = (const float*)d_in[12];
    const float* Wt2 = (const float*)d_in[13];
    const float* bt2 = (const float*)d_in[14];
    const float* Wa  = (const float*)d_in[15];
    const float* ba  = (const float*)d_in[16];
    float* out = (float*)d_out;
    char* ws = (char*)d_ws;

    float* qw = (float*)(ws + OFF_QW);
    float* kw = (float*)(ws + OFF_KW);
    float* vw = (float*)(ws + OFF_VW);
    unsigned short* fragw = (unsigned short*)(ws + OFF_FRAG);
    int* knnIdx = (int*)(ws + OFF_KNN);

    prefrag_kernel<<<48, 256, 0, stream>>>(Wp2, Wt1, Wt2, fragw);
    proj_kernel<<<(2 * NPTS) / 16, 1024, 0, stream>>>(
        features, Wk, bk, Wq, Wks, Wv, qw, kw, vw);
    knn4_kernel<<<(2 * NPTS) / 16, 256, 0, stream>>>(xyzp, knnIdx);
    LocalTransformer_80513456931527_kernel<<<(2 * NPTS) / 4, 256, 0, stream>>>(
        xyzp, features, Wp1, bp1, bp2, bt1, bt2, Wa, ba,
        qw, kw, vw, fragw, knnIdx, out);
}